// Round 1
// baseline (1669.637 us; speedup 1.0000x reference)
//
#include <hip/hip_runtime.h>

// Problem constants (match reference)
constexpr int B = 2, S = 2048, D = 1024, H = 16, E = 8, DH = 64;
constexpr int N = B * S;          // 4096 tokens
constexpr int CAP = 614;          // int(1.2 * N / E)
constexpr float INV_SQRT_D = 0.03125f;   // 1/sqrt(1024)

// =====================================================================
// GEMM: C[M,Nn] = A[M,K] @ W[Nn,K]^T + bias[Nn], batched over blockIdx.z
// 64x64 tile, BK=16, 256 threads, 4x4 microtile.
// =====================================================================
__global__ __launch_bounds__(256) void sgemm_nt(
    const float* __restrict__ A, const float* __restrict__ W,
    const float* __restrict__ bias, float* __restrict__ C,
    int M, int Nn, int K,
    long long sA, long long sW, long long sBias, long long sC)
{
  const long long z = blockIdx.z;
  A += z * sA; W += z * sW; bias += z * sBias; C += z * sC;
  __shared__ float As[16][65];
  __shared__ float Bs[16][65];
  const int tid = threadIdx.x;
  const int tx = tid & 15, ty = tid >> 4;
  const int bm0 = blockIdx.y * 64, bn0 = blockIdx.x * 64;
  const int lr = tid >> 2;            // 0..63
  const int lk = (tid & 3) << 2;      // 0,4,8,12
  float acc[4][4] = {};
  for (int k0 = 0; k0 < K; k0 += 16) {
    int arow = bm0 + lr;
    float4 av = make_float4(0.f, 0.f, 0.f, 0.f);
    if (arow < M) av = *(const float4*)&A[(long long)arow * K + k0 + lk];
    As[lk+0][lr] = av.x; As[lk+1][lr] = av.y; As[lk+2][lr] = av.z; As[lk+3][lr] = av.w;
    float4 wv = *(const float4*)&W[(long long)(bn0 + lr) * K + k0 + lk];
    Bs[lk+0][lr] = wv.x; Bs[lk+1][lr] = wv.y; Bs[lk+2][lr] = wv.z; Bs[lk+3][lr] = wv.w;
    __syncthreads();
    #pragma unroll
    for (int kk = 0; kk < 16; ++kk) {
      float ra[4], rb[4];
      #pragma unroll
      for (int i = 0; i < 4; ++i) ra[i] = As[kk][ty*4+i];
      #pragma unroll
      for (int j = 0; j < 4; ++j) rb[j] = Bs[kk][tx*4+j];
      #pragma unroll
      for (int i = 0; i < 4; ++i)
        #pragma unroll
        for (int j = 0; j < 4; ++j) acc[i][j] += ra[i] * rb[j];
    }
    __syncthreads();
  }
  #pragma unroll
  for (int i = 0; i < 4; ++i) {
    int row = bm0 + ty*4 + i;
    if (row >= M) continue;
    #pragma unroll
    for (int j = 0; j < 4; ++j) {
      int col = bn0 + tx*4 + j;
      C[(long long)row * Nn + col] = acc[i][j] + bias[col];
    }
  }
}

// =====================================================================
// Suffix-sum of v over the sequence axis, per (b,h):
// vsuf[b,s,h,:] = sum_{t>=s} v[b,t,h,:]   (layout [B,S,H*DH] = [N,D])
// =====================================================================
__global__ __launch_bounds__(64) void suffix_v(const float* __restrict__ v,
                                               float* __restrict__ vsuf)
{
  const int bh = blockIdx.x;            // b*H + h
  const int b = bh >> 4, h = bh & 15;
  const int e = threadIdx.x;            // 0..63
  float acc = 0.f;
  for (int s = S - 1; s >= 0; --s) {
    const long long idx = (long long)(b * S + s) * D + h * DH + e;
    acc += v[idx];
    vsuf[idx] = acc;
  }
}

// =====================================================================
// Attention. Faithful masked-zero softmax:
//   out[s] = (sum_{t<=s} e^{qk/32} v_t + vsuf[s+1]) / (sum_{t<=s} e^{qk/32} + (S-1-s))
// Writes hiddens directly in [B,S,H*DH] layout.
// grid (S/64, B*H), 256 threads. Heavy q-tiles scheduled first.
// =====================================================================
__global__ __launch_bounds__(256) void attn_kernel(
    const float* __restrict__ q, const float* __restrict__ k,
    const float* __restrict__ v, const float* __restrict__ vsuf,
    float* __restrict__ hid)
{
  const int bh = blockIdx.y;
  const int b = bh >> 4, h = bh & 15;
  const int s0 = (gridDim.x - 1 - blockIdx.x) * 64;   // reverse: heavy blocks first
  const int tid = threadIdx.x;
  const int tx = tid & 15, ty = tid >> 4;

  __shared__ float qs[64][65];
  __shared__ float ks[64][65];
  __shared__ float vs[64][65];
  __shared__ float wsm[64][65];
  __shared__ float psum[16][65];
  __shared__ float lrow[64];

  // load q tile
  for (int i = tid; i < 64 * 16; i += 256) {
    int r = i >> 4, c = (i & 15) << 2;
    float4 t = *(const float4*)&q[(long long)(b * S + s0 + r) * D + h * DH + c];
    qs[r][c+0] = t.x; qs[r][c+1] = t.y; qs[r][c+2] = t.z; qs[r][c+3] = t.w;
  }

  float oacc[4][4] = {};
  float l_acc = 0.f;

  for (int t0 = 0; t0 <= s0; t0 += 64) {
    __syncthreads();   // prev PV done (also fences qs load on first iter)
    for (int i = tid; i < 64 * 16; i += 256) {
      int r = i >> 4, c = (i & 15) << 2;
      const long long src = (long long)(b * S + t0 + r) * D + h * DH + c;
      float4 tk = *(const float4*)&k[src];
      ks[r][c+0] = tk.x; ks[r][c+1] = tk.y; ks[r][c+2] = tk.z; ks[r][c+3] = tk.w;
      float4 tv = *(const float4*)&v[src];
      vs[r][c+0] = tv.x; vs[r][c+1] = tv.y; vs[r][c+2] = tv.z; vs[r][c+3] = tv.w;
    }
    __syncthreads();
    // scores: sq = ty*4+i, t = tx*4+j
    float sc[4][4] = {};
    for (int kk = 0; kk < 64; ++kk) {
      float ra[4], rb[4];
      #pragma unroll
      for (int i = 0; i < 4; ++i) ra[i] = qs[ty*4+i][kk];
      #pragma unroll
      for (int j = 0; j < 4; ++j) rb[j] = ks[tx*4+j][kk];
      #pragma unroll
      for (int i = 0; i < 4; ++i)
        #pragma unroll
        for (int j = 0; j < 4; ++j) sc[i][j] += ra[i] * rb[j];
    }
    float rsum[4] = {};
    #pragma unroll
    for (int i = 0; i < 4; ++i) {
      const int sg = s0 + ty*4 + i;
      #pragma unroll
      for (int j = 0; j < 4; ++j) {
        const int tg = t0 + tx*4 + j;
        float w = (tg <= sg) ? __expf(sc[i][j] * INV_SQRT_D) : 0.f;
        wsm[ty*4+i][tx*4+j] = w;
        rsum[i] += w;
      }
      psum[tx][ty*4+i] = rsum[i];
    }
    __syncthreads();
    if (tid < 64) {
      float s = 0.f;
      #pragma unroll
      for (int x = 0; x < 16; ++x) s += psum[x][tid];
      l_acc += s;
    }
    // PV: oacc[i][j] += sum_t wsm[sq][t] * vs[t][e]
    for (int kk = 0; kk < 64; ++kk) {
      float ra[4], rb[4];
      #pragma unroll
      for (int i = 0; i < 4; ++i) ra[i] = wsm[ty*4+i][kk];
      #pragma unroll
      for (int j = 0; j < 4; ++j) rb[j] = vs[kk][tx*4+j];
      #pragma unroll
      for (int i = 0; i < 4; ++i)
        #pragma unroll
        for (int j = 0; j < 4; ++j) oacc[i][j] += ra[i] * rb[j];
    }
  }
  __syncthreads();
  if (tid < 64) lrow[tid] = l_acc;
  __syncthreads();
  #pragma unroll
  for (int i = 0; i < 4; ++i) {
    const int sq = ty*4 + i;
    const int sg = s0 + sq;
    const float denom = lrow[sq] + (float)(S - 1 - sg);
    #pragma unroll
    for (int j = 0; j < 4; ++j) {
      const int e = tx*4 + j;
      float suf = (sg + 1 < S) ? vsuf[(long long)(b * S + sg + 1) * D + h * DH + e] : 0.f;
      hid[(long long)(b * S + sg) * D + h * DH + e] = (oacc[i][j] + suf) / denom;
    }
  }
}

// =====================================================================
// Router: logits = x @ Wsw^T + bsw ; route = argmax softmax; prob of max.
// one wave per token.
// =====================================================================
__global__ __launch_bounds__(64) void router_kernel(
    const float* __restrict__ x, const float* __restrict__ Wsw,
    const float* __restrict__ bsw, int* __restrict__ routes,
    float* __restrict__ rprob)
{
  const int i = blockIdx.x;
  const int lane = threadIdx.x;
  float p[E] = {};
  for (int d = lane; d < D; d += 64) {
    float xv = x[(long long)i * D + d];
    #pragma unroll
    for (int e = 0; e < E; ++e) p[e] += xv * Wsw[e * D + d];
  }
  #pragma unroll
  for (int off = 32; off; off >>= 1)
    #pragma unroll
    for (int e = 0; e < E; ++e) p[e] += __shfl_xor(p[e], off);
  if (lane == 0) {
    float m = -1e30f; int arg = 0;
    #pragma unroll
    for (int e = 0; e < E; ++e) {
      float l = p[e] + bsw[e];
      if (l > m) { m = l; arg = e; }   // strict >: first max (matches argmax)
      p[e] = l;
    }
    float sum = 0.f;
    #pragma unroll
    for (int e = 0; e < E; ++e) sum += __expf(p[e] - m);
    routes[i] = arg;
    rprob[i] = 1.f / sum;              // softmax prob of the max logit
  }
}

// =====================================================================
// Sequential-order capacity scan (cumsum over tokens). Single block.
// slot[i] = route*CAP + pos if kept else -1
// =====================================================================
__global__ __launch_bounds__(256) void scan_kernel(const int* __restrict__ routes,
                                                   int* __restrict__ slot)
{
  __shared__ int hist[256][E];
  const int tid = threadIdx.x;
  const int per = N / 256;   // 16
  int cnt[E] = {};
  for (int j = 0; j < per; ++j) cnt[routes[tid * per + j]]++;
  #pragma unroll
  for (int e = 0; e < E; ++e) hist[tid][e] = cnt[e];
  __syncthreads();
  if (tid < E) {            // serial exclusive scan per expert (256 iters, tiny)
    int run = 0;
    for (int t = 0; t < 256; ++t) { int tmp = hist[t][tid]; hist[t][tid] = run; run += tmp; }
  }
  __syncthreads();
  int run[E];
  #pragma unroll
  for (int e = 0; e < E; ++e) run[e] = hist[tid][e];
  for (int j = 0; j < per; ++j) {
    int i = tid * per + j;
    int r = routes[i];
    int pos = run[r]++;
    slot[i] = (pos < CAP) ? r * CAP + pos : -1;
  }
}

// =====================================================================
// Dispatch: scatter kept token rows into expert_in[slot]
// =====================================================================
__global__ __launch_bounds__(256) void dispatch_kernel(
    const float* __restrict__ x, const int* __restrict__ slot,
    float* __restrict__ expert_in)
{
  const int i = blockIdx.x;
  const int sl = slot[i];
  if (sl < 0) return;
  const float4* src = (const float4*)&x[(long long)i * D];
  float4* dst = (float4*)&expert_in[(long long)sl * D];
  dst[threadIdx.x] = src[threadIdx.x];
}

// =====================================================================
// Finalize: gather expert output (or passthrough), *route_prob, +embed,
// LayerNorm. One block per token.
// =====================================================================
__global__ __launch_bounds__(256) void finalize_kernel(
    const float* __restrict__ x, const float* __restrict__ eout,
    const int* __restrict__ slot, const float* __restrict__ rprob,
    const float* __restrict__ embed, const float* __restrict__ gamma,
    const float* __restrict__ beta, float* __restrict__ out)
{
  const int i = blockIdx.x;
  const int tid = threadIdx.x;
  const int sl = slot[i];
  const float rp = rprob[i];
  const float4* src = (sl >= 0) ? (const float4*)&eout[(long long)sl * D]
                                : (const float4*)&x[(long long)i * D];
  float4 yv = src[tid];
  float4 ev = ((const float4*)&embed[(long long)i * D])[tid];
  float v0 = yv.x * rp + ev.x;
  float v1 = yv.y * rp + ev.y;
  float v2 = yv.z * rp + ev.z;
  float v3 = yv.w * rp + ev.w;
  float s1 = v0 + v1 + v2 + v3;
  float s2 = v0*v0 + v1*v1 + v2*v2 + v3*v3;
  #pragma unroll
  for (int off = 32; off; off >>= 1) {
    s1 += __shfl_xor(s1, off);
    s2 += __shfl_xor(s2, off);
  }
  __shared__ float wsum[4], wsq[4];
  const int wid = tid >> 6, lid = tid & 63;
  if (lid == 0) { wsum[wid] = s1; wsq[wid] = s2; }
  __syncthreads();
  float tot  = wsum[0] + wsum[1] + wsum[2] + wsum[3];
  float tot2 = wsq[0] + wsq[1] + wsq[2] + wsq[3];
  const float mean = tot * (1.f / D);
  const float var = tot2 * (1.f / D) - mean * mean;
  const float rstd = rsqrtf(var + 1e-5f);
  float4 gv = ((const float4*)gamma)[tid];
  float4 bv = ((const float4*)beta)[tid];
  float4 ov;
  ov.x = (v0 - mean) * rstd * gv.x + bv.x;
  ov.y = (v1 - mean) * rstd * gv.y + bv.y;
  ov.z = (v2 - mean) * rstd * gv.z + bv.z;
  ov.w = (v3 - mean) * rstd * gv.w + bv.w;
  ((float4*)&out[(long long)i * D])[tid] = ov;
}

// =====================================================================
extern "C" void kernel_launch(void* const* d_in, const int* in_sizes, int n_in,
                              void* d_out, int out_size, void* d_ws, size_t ws_size,
                              hipStream_t stream) {
  const float* embed = (const float*)d_in[0];
  const float* Wq = (const float*)d_in[1];
  const float* bq = (const float*)d_in[2];
  const float* Wk = (const float*)d_in[3];
  const float* bk = (const float*)d_in[4];
  const float* Wv = (const float*)d_in[5];
  const float* bv = (const float*)d_in[6];
  const float* We = (const float*)d_in[7];
  const float* be = (const float*)d_in[8];
  const float* Wsw = (const float*)d_in[9];
  const float* bsw = (const float*)d_in[10];
  const float* gamma = (const float*)d_in[11];
  const float* beta = (const float*)d_in[12];
  float* out = (float*)d_out;

  // Workspace layout (floats). q,k dead after attention -> expert_in aliases
  // them; v,vsuf dead after attention -> expert_out aliases them.
  constexpr long long TOK = (long long)N * D;            // 4,194,304
  float* ws = (float*)d_ws;
  float* q    = ws + 0 * TOK;
  float* k    = ws + 1 * TOK;
  float* v    = ws + 2 * TOK;
  float* vsuf = ws + 3 * TOK;
  float* hid  = ws + 4 * TOK;
  float* expert_in  = ws + 0 * TOK;                      // alias q+k (needs 5.03M floats <= 8.39M)
  float* expert_out = ws + 2 * TOK;                      // alias v+vsuf
  int*   routes = (int*)(ws + 5 * TOK);
  int*   slot   = (int*)(ws + 5 * TOK) + N;
  float* rprob  = (float*)((int*)(ws + 5 * TOK) + 2 * N);

  // 1-3. QKV projections
  dim3 gemm_grid(D / 64, N / 64, 1);
  sgemm_nt<<<gemm_grid, 256, 0, stream>>>(embed, Wq, bq, q, N, D, D, 0, 0, 0, 0);
  sgemm_nt<<<gemm_grid, 256, 0, stream>>>(embed, Wk, bk, k, N, D, D, 0, 0, 0, 0);
  sgemm_nt<<<gemm_grid, 256, 0, stream>>>(embed, Wv, bv, v, N, D, D, 0, 0, 0, 0);
  // 4. suffix sums of v (for masked-zero softmax contribution)
  suffix_v<<<B * H, 64, 0, stream>>>(v, vsuf);
  // 5. attention -> hiddens [B,S,D]
  attn_kernel<<<dim3(S / 64, B * H), 256, 0, stream>>>(q, k, v, vsuf, hid);
  // 6. router
  router_kernel<<<N, 64, 0, stream>>>(hid, Wsw, bsw, routes, rprob);
  // 7. capacity scan (sequential order)
  scan_kernel<<<1, 256, 0, stream>>>(routes, slot);
  // 8. dispatch
  dispatch_kernel<<<N, 256, 0, stream>>>(hid, slot, expert_in);
  // 9. expert GEMMs (batched over E)
  dim3 egrid(D / 64, (CAP + 63) / 64, E);
  sgemm_nt<<<egrid, 256, 0, stream>>>(expert_in, We, be, expert_out,
                                      CAP, D, D,
                                      (long long)CAP * D, (long long)D * D, D,
                                      (long long)CAP * D);
  // 10. gather + combine + residual + LayerNorm
  finalize_kernel<<<N, 256, 0, stream>>>(hid, expert_out, slot, rprob,
                                         embed, gamma, beta, out);
}

// Round 2
// 996.370 us; speedup vs baseline: 1.6757x; 1.6757x over previous
//
#include <hip/hip_runtime.h>

// Problem constants (match reference)
constexpr int B = 2, S = 2048, D = 1024, H = 16, E = 8, DH = 64;
constexpr int N = B * S;          // 4096 tokens
constexpr int CAP = 614;          // int(1.2 * N / E) -- capacity check
constexpr int ECAP = 640;         // padded rows per expert (5 * 128 tiles)
constexpr float INV_SQRT_D = 0.03125f;   // 1/sqrt(1024)

typedef __bf16 bf16x8 __attribute__((ext_vector_type(8)));
typedef float f32x4 __attribute__((ext_vector_type(4)));

__device__ __forceinline__ ushort f2bf(float x) {
  __bf16 h = (__bf16)x;
  return __builtin_bit_cast(unsigned short, h);
}
__device__ __forceinline__ float bf2f(ushort u) {
  __bf16 h = __builtin_bit_cast(__bf16, u);
  return (float)h;
}
// 16B direct global->LDS. LDS dest must be wave-uniform base (+ lane*16 by HW).
__device__ __forceinline__ void gld16(const void* g, void* l) {
  __builtin_amdgcn_global_load_lds(
      (const __attribute__((address_space(1))) unsigned int*)g,
      (__attribute__((address_space(3))) unsigned int*)l, 16, 0, 0);
}

// =====================================================================
// fp32 -> bf16 hi/lo pair. in [rows][1024] f32, out [rows][2048] bf16
// (cols 0-1023 = hi, 1024-2047 = lo). 1024 floats per row, 4/thread.
// =====================================================================
__global__ __launch_bounds__(256) void cvt_pair(const float* __restrict__ in,
                                                ushort* __restrict__ out)
{
  const long long idx4 = (long long)blockIdx.x * 256 + threadIdx.x;  // float4 idx
  const float4 xv = ((const float4*)in)[idx4];
  const long long row = idx4 >> 8;            // 256 float4 per row
  const int col = (int)((idx4 & 255) << 2);
  float xs[4] = {xv.x, xv.y, xv.z, xv.w};
  ushort4 hi, lo;
  ushort* hp = (ushort*)&hi; ushort* lp = (ushort*)&lo;
  #pragma unroll
  for (int c = 0; c < 4; ++c) {
    ushort h = f2bf(xs[c]);
    hp[c] = h;
    lp[c] = f2bf(xs[c] - bf2f(h));
  }
  *(ushort4*)&out[row * 2048 + col] = hi;
  *(ushort4*)&out[row * 2048 + 1024 + col] = lo;
}

// plain fp32 -> bf16, flat
__global__ __launch_bounds__(256) void cvt_plain(const float* __restrict__ in,
                                                 ushort* __restrict__ out)
{
  const long long idx4 = (long long)blockIdx.x * 256 + threadIdx.x;
  const float4 xv = ((const float4*)in)[idx4];
  ushort4 o;
  o.x = f2bf(xv.x); o.y = f2bf(xv.y); o.z = f2bf(xv.z); o.w = f2bf(xv.w);
  *(ushort4*)&out[idx4 * 4] = o;
}

// =====================================================================
// bf16 MFMA GEMM: C[128-tile grid] = A[M,K]@W[Nn=1024,K]^T + bias.
// TRIPLE: hi/lo split-bf16, logical K'=3072 mapped onto pair arrays
//   [hi|lo] of width 2048:  k'<2048 -> A col k' ; k'>=2048 -> A col k'-2048
//                           k'<1024 -> W col k' ; k'>=1024 -> W col k'-1024
//   giving hi*hi + lo*hi + hi*lo (error ~2^-18, routing-safe).
// 128x128 tile, BK=64, 4 waves (2x2), 16x16x32 MFMA, 4x4 frags/wave.
// Staging: global_load_lds w=16, source XOR-(row&7) unit swizzle; reads
// apply the same XOR -> conflict-free ds_read_b128 (rule #21: both sides).
// =====================================================================
template <bool TRIPLE>
__global__ __launch_bounds__(256) void mfma_gemm(
    const ushort* __restrict__ A, const ushort* __restrict__ W,
    const float* __restrict__ b0, const float* __restrict__ b1,
    const float* __restrict__ b2, float* __restrict__ C,
    long long strideA, long long strideW, long long strideC,
    long long biasStride, int biasSel)
{
  constexpr int KA = TRIPLE ? 2048 : 1024;
  constexpr int KW = TRIPLE ? 2048 : 1024;
  constexpr int NSTEP = TRIPLE ? 48 : 16;
  const int z = blockIdx.z;
  A += (long long)z * strideA;
  W += (long long)z * strideW;
  C += (long long)z * strideC;
  const float* bp = biasSel ? (z == 0 ? b0 : (z == 1 ? b1 : b2))
                            : b0 + (long long)z * biasStride;

  __shared__ char smem[32768] __attribute__((aligned(128)));  // A:0-16K, B:16K-32K
  const int tid = threadIdx.x;
  const int lane = tid & 63;
  const int lrow = lane & 15;
  const int lk = lane >> 4;           // 0..3
  const int wv = tid >> 6;
  const int rAc = (wv >> 1) * 64;
  const int rBc = (wv & 1) * 64;
  const int bm0 = blockIdx.y * 128;
  const int bn0 = blockIdx.x * 128;
  const int srow = tid >> 3;          // staging row within issue (0..31)
  const int su = tid & 7;             // staging 16B-unit

  f32x4 acc[4][4] = {};

  for (int step = 0; step < NSTEP; ++step) {
    const int k0 = step * 64;
    int srcA, srcB;
    if (TRIPLE) {
      srcA = (k0 < 2048) ? k0 : k0 - 2048;
      srcB = (k0 < 1024) ? k0 : k0 - 1024;
    } else { srcA = k0; srcB = k0; }
    __syncthreads();                  // prior compute done before overwrite
    #pragma unroll
    for (int i = 0; i < 4; ++i) {
      const int row = i * 32 + srow;
      const int u = su ^ (row & 7);   // pre-swizzled global source
      gld16(A + (long long)(bm0 + row) * KA + srcA + u * 8,
            smem + i * 4096 + wv * 1024);
      gld16(W + (long long)(bn0 + row) * KW + srcB + u * 8,
            smem + 16384 + i * 4096 + wv * 1024);
    }
    asm volatile("s_waitcnt vmcnt(0)" ::: "memory");
    __syncthreads();
    #pragma unroll
    for (int h = 0; h < 2; ++h) {     // two K=32 halves of BK=64
      bf16x8 af[4], bfr[4];
      #pragma unroll
      for (int i = 0; i < 4; ++i) {
        const int row = rAc + i * 16 + lrow;
        const int u = (h * 4 + lk) ^ (row & 7);
        af[i] = *(const bf16x8*)(smem + row * 128 + u * 16);
      }
      #pragma unroll
      for (int j = 0; j < 4; ++j) {
        const int row = rBc + j * 16 + lrow;
        const int u = (h * 4 + lk) ^ (row & 7);
        bfr[j] = *(const bf16x8*)(smem + 16384 + row * 128 + u * 16);
      }
      #pragma unroll
      for (int i = 0; i < 4; ++i)
        #pragma unroll
        for (int j = 0; j < 4; ++j)
          acc[i][j] = __builtin_amdgcn_mfma_f32_16x16x32_bf16(
              af[i], bfr[j], acc[i][j], 0, 0, 0);
    }
  }
  // epilogue: C[row][col] = acc + bias[col]; C/D: col=lane&15, row=(lane>>4)*4+r
  const int rg = (lane >> 4) * 4;
  #pragma unroll
  for (int j = 0; j < 4; ++j) {
    const int col = bn0 + rBc + j * 16 + (lane & 15);
    const float bj = bp[col];
    #pragma unroll
    for (int i = 0; i < 4; ++i) {
      const long long rbase = bm0 + rAc + i * 16 + rg;
      #pragma unroll
      for (int r = 0; r < 4; ++r)
        C[(rbase + r) * 1024 + col] = acc[i][j][r] + bj;
    }
  }
}

// =====================================================================
// Parallel suffix-sum of v (per b,h over S). Two passes over 32 chunks.
// =====================================================================
__global__ __launch_bounds__(64) void vchunk_sum(const float* __restrict__ v,
                                                 float* __restrict__ csum)
{
  const int bh = blockIdx.x, c = blockIdx.y, e = threadIdx.x;
  const int b = bh >> 4, h = bh & 15;
  const long long base = (long long)(b * S + c * 64) * D + h * DH + e;
  float s = 0.f;
  for (int t = 0; t < 64; ++t) s += v[base + (long long)t * D];
  csum[((long long)bh * 32 + c) * 64 + e] = s;
}

__global__ __launch_bounds__(64) void vsuffix_emit(const float* __restrict__ v,
                                                   const float* __restrict__ csum,
                                                   float* __restrict__ vsuf)
{
  const int bh = blockIdx.x, c = blockIdx.y, e = threadIdx.x;
  const int b = bh >> 4, h = bh & 15;
  float acc = 0.f;
  for (int cc = c + 1; cc < 32; ++cc)
    acc += csum[((long long)bh * 32 + cc) * 64 + e];
  const long long base = (long long)(b * S + c * 64) * D + h * DH + e;
  for (int t = 63; t >= 0; --t) {
    acc += v[base + (long long)t * D];
    vsuf[base + (long long)t * D] = acc;
  }
}

// =====================================================================
// Attention (fp32, unchanged this round). Faithful masked-zero softmax:
//   out[s] = (sum_{t<=s} e^{qk/32} v_t + vsuf[s+1]) / (sum_{t<=s} e^{qk/32} + (S-1-s))
// =====================================================================
__global__ __launch_bounds__(256) void attn_kernel(
    const float* __restrict__ q, const float* __restrict__ k,
    const float* __restrict__ v, const float* __restrict__ vsuf,
    float* __restrict__ hid)
{
  const int bh = blockIdx.y;
  const int b = bh >> 4, h = bh & 15;
  const int s0 = (gridDim.x - 1 - blockIdx.x) * 64;   // heavy blocks first
  const int tid = threadIdx.x;
  const int tx = tid & 15, ty = tid >> 4;

  __shared__ float qs[64][65];
  __shared__ float ks[64][65];
  __shared__ float vs[64][65];
  __shared__ float wsm[64][65];
  __shared__ float psum[16][65];
  __shared__ float lrow[64];

  for (int i = tid; i < 64 * 16; i += 256) {
    int r = i >> 4, c = (i & 15) << 2;
    float4 t = *(const float4*)&q[(long long)(b * S + s0 + r) * D + h * DH + c];
    qs[r][c+0] = t.x; qs[r][c+1] = t.y; qs[r][c+2] = t.z; qs[r][c+3] = t.w;
  }

  float oacc[4][4] = {};
  float l_acc = 0.f;

  for (int t0 = 0; t0 <= s0; t0 += 64) {
    __syncthreads();
    for (int i = tid; i < 64 * 16; i += 256) {
      int r = i >> 4, c = (i & 15) << 2;
      const long long src = (long long)(b * S + t0 + r) * D + h * DH + c;
      float4 tk = *(const float4*)&k[src];
      ks[r][c+0] = tk.x; ks[r][c+1] = tk.y; ks[r][c+2] = tk.z; ks[r][c+3] = tk.w;
      float4 tv = *(const float4*)&v[src];
      vs[r][c+0] = tv.x; vs[r][c+1] = tv.y; vs[r][c+2] = tv.z; vs[r][c+3] = tv.w;
    }
    __syncthreads();
    float sc[4][4] = {};
    for (int kk = 0; kk < 64; ++kk) {
      float ra[4], rb[4];
      #pragma unroll
      for (int i = 0; i < 4; ++i) ra[i] = qs[ty*4+i][kk];
      #pragma unroll
      for (int j = 0; j < 4; ++j) rb[j] = ks[tx*4+j][kk];
      #pragma unroll
      for (int i = 0; i < 4; ++i)
        #pragma unroll
        for (int j = 0; j < 4; ++j) sc[i][j] += ra[i] * rb[j];
    }
    float rsum[4] = {};
    #pragma unroll
    for (int i = 0; i < 4; ++i) {
      const int sg = s0 + ty*4 + i;
      #pragma unroll
      for (int j = 0; j < 4; ++j) {
        const int tg = t0 + tx*4 + j;
        float w = (tg <= sg) ? __expf(sc[i][j] * INV_SQRT_D) : 0.f;
        wsm[ty*4+i][tx*4+j] = w;
        rsum[i] += w;
      }
      psum[tx][ty*4+i] = rsum[i];
    }
    __syncthreads();
    if (tid < 64) {
      float s = 0.f;
      #pragma unroll
      for (int x = 0; x < 16; ++x) s += psum[x][tid];
      l_acc += s;
    }
    for (int kk = 0; kk < 64; ++kk) {
      float ra[4], rb[4];
      #pragma unroll
      for (int i = 0; i < 4; ++i) ra[i] = wsm[ty*4+i][kk];
      #pragma unroll
      for (int j = 0; j < 4; ++j) rb[j] = vs[kk][tx*4+j];
      #pragma unroll
      for (int i = 0; i < 4; ++i)
        #pragma unroll
        for (int j = 0; j < 4; ++j) oacc[i][j] += ra[i] * rb[j];
    }
  }
  __syncthreads();
  if (tid < 64) lrow[tid] = l_acc;
  __syncthreads();
  #pragma unroll
  for (int i = 0; i < 4; ++i) {
    const int sq = ty*4 + i;
    const int sg = s0 + sq;
    const float denom = lrow[sq] + (float)(S - 1 - sg);
    #pragma unroll
    for (int j = 0; j < 4; ++j) {
      const int e = tx*4 + j;
      float suf = (sg + 1 < S) ? vsuf[(long long)(b * S + sg + 1) * D + h * DH + e] : 0.f;
      hid[(long long)(b * S + sg) * D + h * DH + e] = (oacc[i][j] + suf) / denom;
    }
  }
}

// =====================================================================
// Router: 4 tokens per block (one per wave), vectorized.
// =====================================================================
__global__ __launch_bounds__(256) void router_kernel(
    const float* __restrict__ x, const float* __restrict__ Wsw,
    const float* __restrict__ bsw, int* __restrict__ routes,
    float* __restrict__ rprob)
{
  const int w = threadIdx.x >> 6, lane = threadIdx.x & 63;
  const int i = blockIdx.x * 4 + w;
  float p[E] = {};
  const float4* xr = (const float4*)(x + (long long)i * D);
  #pragma unroll
  for (int t = 0; t < 4; ++t) {
    float4 xv = xr[lane + 64 * t];
    #pragma unroll
    for (int e = 0; e < E; ++e) {
      float4 wv = ((const float4*)(Wsw + e * D))[lane + 64 * t];
      p[e] += xv.x * wv.x + xv.y * wv.y + xv.z * wv.z + xv.w * wv.w;
    }
  }
  #pragma unroll
  for (int off = 32; off; off >>= 1)
    #pragma unroll
    for (int e = 0; e < E; ++e) p[e] += __shfl_xor(p[e], off);
  if (lane == 0) {
    float m = -1e30f; int arg = 0;
    #pragma unroll
    for (int e = 0; e < E; ++e) {
      float l = p[e] + bsw[e];
      if (l > m) { m = l; arg = e; }
      p[e] = l;
    }
    float sum = 0.f;
    #pragma unroll
    for (int e = 0; e < E; ++e) sum += __expf(p[e] - m);
    routes[i] = arg;
    rprob[i] = 1.f / sum;
  }
}

// =====================================================================
// Sequential-order capacity scan. slot = route*ECAP + pos (kept) else -1.
// =====================================================================
__global__ __launch_bounds__(256) void scan_kernel(const int* __restrict__ routes,
                                                   int* __restrict__ slot)
{
  __shared__ int hist[256][E];
  const int tid = threadIdx.x;
  const int per = N / 256;   // 16
  int cnt[E] = {};
  for (int j = 0; j < per; ++j) cnt[routes[tid * per + j]]++;
  #pragma unroll
  for (int e = 0; e < E; ++e) hist[tid][e] = cnt[e];
  __syncthreads();
  if (tid < E) {
    int run = 0;
    for (int t = 0; t < 256; ++t) { int tmp = hist[t][tid]; hist[t][tid] = run; run += tmp; }
  }
  __syncthreads();
  int run[E];
  #pragma unroll
  for (int e = 0; e < E; ++e) run[e] = hist[tid][e];
  for (int j = 0; j < per; ++j) {
    int i = tid * per + j;
    int r = routes[i];
    int pos = run[r]++;
    slot[i] = (pos < CAP) ? r * ECAP + pos : -1;
  }
}

// =====================================================================
// Dispatch: scatter kept tokens (fp32 -> bf16) into expert_in[slot]
// =====================================================================
__global__ __launch_bounds__(256) void dispatch_kernel(
    const float* __restrict__ x, const int* __restrict__ slot,
    ushort* __restrict__ expert_in)
{
  const int i = blockIdx.x;
  const int sl = slot[i];
  if (sl < 0) return;
  float4 xv = ((const float4*)&x[(long long)i * D])[threadIdx.x];
  ushort4 o;
  o.x = f2bf(xv.x); o.y = f2bf(xv.y); o.z = f2bf(xv.z); o.w = f2bf(xv.w);
  ((ushort4*)&expert_in[(long long)sl * D])[threadIdx.x] = o;
}

// =====================================================================
// Finalize: gather/passthrough, *route_prob, +embed, LayerNorm.
// =====================================================================
__global__ __launch_bounds__(256) void finalize_kernel(
    const float* __restrict__ x, const float* __restrict__ eout,
    const int* __restrict__ slot, const float* __restrict__ rprob,
    const float* __restrict__ embed, const float* __restrict__ gamma,
    const float* __restrict__ beta, float* __restrict__ out)
{
  const int i = blockIdx.x;
  const int tid = threadIdx.x;
  const int sl = slot[i];
  const float rp = rprob[i];
  const float4* src = (sl >= 0) ? (const float4*)&eout[(long long)sl * D]
                                : (const float4*)&x[(long long)i * D];
  float4 yv = src[tid];
  float4 ev = ((const float4*)&embed[(long long)i * D])[tid];
  float v0 = yv.x * rp + ev.x;
  float v1 = yv.y * rp + ev.y;
  float v2 = yv.z * rp + ev.z;
  float v3 = yv.w * rp + ev.w;
  float s1 = v0 + v1 + v2 + v3;
  float s2 = v0*v0 + v1*v1 + v2*v2 + v3*v3;
  #pragma unroll
  for (int off = 32; off; off >>= 1) {
    s1 += __shfl_xor(s1, off);
    s2 += __shfl_xor(s2, off);
  }
  __shared__ float wsum[4], wsq[4];
  const int wid = tid >> 6, lid = tid & 63;
  if (lid == 0) { wsum[wid] = s1; wsq[wid] = s2; }
  __syncthreads();
  float tot  = wsum[0] + wsum[1] + wsum[2] + wsum[3];
  float tot2 = wsq[0] + wsq[1] + wsq[2] + wsq[3];
  const float mean = tot * (1.f / D);
  const float var = tot2 * (1.f / D) - mean * mean;
  const float rstd = rsqrtf(var + 1e-5f);
  float4 gv = ((const float4*)gamma)[tid];
  float4 bv = ((const float4*)beta)[tid];
  float4 ov;
  ov.x = (v0 - mean) * rstd * gv.x + bv.x;
  ov.y = (v1 - mean) * rstd * gv.y + bv.y;
  ov.z = (v2 - mean) * rstd * gv.z + bv.z;
  ov.w = (v3 - mean) * rstd * gv.w + bv.w;
  ((float4*)&out[(long long)i * D])[tid] = ov;
}

// =====================================================================
extern "C" void kernel_launch(void* const* d_in, const int* in_sizes, int n_in,
                              void* d_out, int out_size, void* d_ws, size_t ws_size,
                              hipStream_t stream) {
  const float* embed = (const float*)d_in[0];
  const float* Wq = (const float*)d_in[1];
  const float* bq = (const float*)d_in[2];
  const float* Wk = (const float*)d_in[3];
  const float* bk = (const float*)d_in[4];
  const float* Wv = (const float*)d_in[5];
  const float* bv = (const float*)d_in[6];
  const float* We = (const float*)d_in[7];
  const float* be = (const float*)d_in[8];
  const float* Wsw = (const float*)d_in[9];
  const float* bsw = (const float*)d_in[10];
  const float* gamma = (const float*)d_in[11];
  const float* beta = (const float*)d_in[12];
  float* out = (float*)d_out;

  // Workspace regions (floats). Lifetime-aliased; peak = 5*TOK + ~0.3MB.
  constexpr long long TOK = (long long)N * D;            // 4,194,304
  float* ws = (float*)d_ws;
  ushort* epair = (ushort*)ws;                 // R0: embed hi/lo pairs (16.8MB)
  float*  hid   = ws;                          // R0 reuse: hiddens (after GEMMs)
  float* q = ws + 1 * TOK;                     // R1
  float* k = ws + 2 * TOK;
  float* v = ws + 3 * TOK;
  ushort* wpair = (ushort*)(ws + 4 * TOK);     // R2: W hi/lo (12.6MB)
  float*  vsuf  = ws + 4 * TOK;                // R2 reuse: suffix sums
  ushort* webf  = (ushort*)(ws + 4 * TOK);     // R2 reuse: We bf16 (16.8MB)
  ushort* expert_in  = (ushort*)(ws + 1 * TOK);// R1 reuse (over q)
  float*  expert_out = ws + 2 * TOK;           // R1 reuse (over k,v)
  int*   routes = (int*)(ws + 5 * TOK);        // R3
  int*   slot   = routes + N;
  float* rprob  = (float*)(slot + N);
  float* csum   = rprob + N;                   // 32*32*64 floats

  // 1. conversions: embed -> hi/lo pairs; Wq/Wk/Wv -> hi/lo pairs
  cvt_pair<<<N * D / 1024, 256, 0, stream>>>(embed, epair);
  cvt_pair<<<D * D / 1024, 256, 0, stream>>>(Wq, wpair + 0ll * D * 2048);
  cvt_pair<<<D * D / 1024, 256, 0, stream>>>(Wk, wpair + 1ll * D * 2048);
  cvt_pair<<<D * D / 1024, 256, 0, stream>>>(Wv, wpair + 2ll * D * 2048);
  // 2. QKV projections: split-bf16 MFMA GEMM (K'=3072)
  mfma_gemm<true><<<dim3(8, 32, 3), 256, 0, stream>>>(
      epair, wpair, bq, bk, bv, q,
      0, (long long)D * 2048, TOK, 0, 1);
  // 3. suffix sums of v
  vchunk_sum<<<dim3(B * H, 32), 64, 0, stream>>>(v, csum);
  vsuffix_emit<<<dim3(B * H, 32), 64, 0, stream>>>(v, csum, vsuf);
  // 4. attention -> hiddens
  attn_kernel<<<dim3(S / 64, B * H), 256, 0, stream>>>(q, k, v, vsuf, hid);
  // 5. router
  router_kernel<<<N / 4, 256, 0, stream>>>(hid, Wsw, bsw, routes, rprob);
  // 6. capacity scan
  scan_kernel<<<1, 256, 0, stream>>>(routes, slot);
  // 7. We -> bf16 (overwrites vsuf region; after attention)
  cvt_plain<<<(int)((long long)E * D * D / 1024), 256, 0, stream>>>(We, webf);
  // 8. dispatch tokens -> expert_in (bf16)
  dispatch_kernel<<<N, 256, 0, stream>>>(hid, slot, expert_in);
  // 9. expert GEMMs: plain bf16 MFMA (K=1024), M padded to 640
  mfma_gemm<false><<<dim3(8, ECAP / 128, E), 256, 0, stream>>>(
      expert_in, webf, be, nullptr, nullptr, expert_out,
      (long long)ECAP * D, (long long)D * D, (long long)ECAP * D,
      (long long)D, 0);
  // 10. gather + combine + residual + LayerNorm
  finalize_kernel<<<N, 256, 0, stream>>>(hid, expert_out, slot, rprob,
                                         embed, gamma, beta, out);
}

// Round 4
// 478.137 us; speedup vs baseline: 3.4920x; 2.0839x over previous
//
#include <hip/hip_runtime.h>

// Problem constants (match reference)
constexpr int B = 2, S = 2048, D = 1024, H = 16, E = 8, DH = 64;
constexpr int N = B * S;          // 4096 tokens
constexpr int CAP = 614;          // int(1.2 * N / E) -- capacity check
constexpr int ECAP = 640;         // padded rows per expert (5 * 128 tiles)
constexpr float INV_SQRT_D = 0.03125f;   // 1/sqrt(1024)

typedef __bf16 bf16x8 __attribute__((ext_vector_type(8)));
typedef float f32x4 __attribute__((ext_vector_type(4)));

__device__ __forceinline__ ushort f2bf(float x) {
  __bf16 h = (__bf16)x;
  return __builtin_bit_cast(unsigned short, h);
}
__device__ __forceinline__ float bf2f(ushort u) {
  __bf16 h = __builtin_bit_cast(__bf16, u);
  return (float)h;
}
// 16B direct global->LDS. LDS dest is wave-uniform base (+ lane*16 by HW).
__device__ __forceinline__ void gld16(const void* g, void* l) {
  __builtin_amdgcn_global_load_lds(
      (const __attribute__((address_space(1))) unsigned int*)g,
      (__attribute__((address_space(3))) unsigned int*)l, 16, 0, 0);
}

// =====================================================================
// fp32 -> bf16 hi/lo pair. in [rows][1024] f32, out [rows][2048] bf16
// =====================================================================
__global__ __launch_bounds__(256) void cvt_pair(const float* __restrict__ in,
                                                ushort* __restrict__ out)
{
  const long long idx4 = (long long)blockIdx.x * 256 + threadIdx.x;  // float4 idx
  const float4 xv = ((const float4*)in)[idx4];
  const long long row = idx4 >> 8;            // 256 float4 per row
  const int col = (int)((idx4 & 255) << 2);
  float xs[4] = {xv.x, xv.y, xv.z, xv.w};
  ushort4 hi, lo;
  ushort* hp = (ushort*)&hi; ushort* lp = (ushort*)&lo;
  #pragma unroll
  for (int c = 0; c < 4; ++c) {
    ushort h = f2bf(xs[c]);
    hp[c] = h;
    lp[c] = f2bf(xs[c] - bf2f(h));
  }
  *(ushort4*)&out[row * 2048 + col] = hi;
  *(ushort4*)&out[row * 2048 + 1024 + col] = lo;
}

// plain fp32 -> bf16, flat
__global__ __launch_bounds__(256) void cvt_plain(const float* __restrict__ in,
                                                 ushort* __restrict__ out)
{
  const long long idx4 = (long long)blockIdx.x * 256 + threadIdx.x;
  const float4 xv = ((const float4*)in)[idx4];
  ushort4 o;
  o.x = f2bf(xv.x); o.y = f2bf(xv.y); o.z = f2bf(xv.z); o.w = f2bf(xv.w);
  *(ushort4*)&out[idx4 * 4] = o;
}

// =====================================================================
// bf16 MFMA GEMM.  TRIPLE: hi/lo split, logical K'=3072 (see R2 notes).
// EPI=0: C f32 [M][1024] + bias.  EPI=1 (QKV): write bf16 hi/lo pairs:
//   z=0/1 (q/k): pairout[z][bh][s][128]  (cols 0-63 hi, 64-127 lo)
//   z=2   (v)  : vtp[bh][sec][e][2048]   (transposed, sec=hi/lo)
// =====================================================================
template <bool TRIPLE, int EPI>
__global__ __launch_bounds__(256) void mfma_gemm(
    const ushort* __restrict__ A, const ushort* __restrict__ W,
    const float* __restrict__ b0, const float* __restrict__ b1,
    const float* __restrict__ b2, float* __restrict__ C,
    ushort* __restrict__ pairout,
    long long strideA, long long strideW, long long strideC,
    long long biasStride, int biasSel)
{
  constexpr int KA = TRIPLE ? 2048 : 1024;
  constexpr int KW = TRIPLE ? 2048 : 1024;
  constexpr int NSTEP = TRIPLE ? 48 : 16;
  const int z = blockIdx.z;
  A += (long long)z * strideA;
  W += (long long)z * strideW;
  C += (long long)z * strideC;
  const float* bp = biasSel ? (z == 0 ? b0 : (z == 1 ? b1 : b2))
                            : b0 + (long long)z * biasStride;

  __shared__ char smem[32768] __attribute__((aligned(128)));
  const int tid = threadIdx.x;
  const int lane = tid & 63;
  const int lrow = lane & 15;
  const int lk = lane >> 4;
  const int wv = tid >> 6;
  const int rAc = (wv >> 1) * 64;
  const int rBc = (wv & 1) * 64;
  const int bm0 = blockIdx.y * 128;
  const int bn0 = blockIdx.x * 128;
  const int srow = tid >> 3;
  const int su = tid & 7;

  f32x4 acc[4][4] = {};

  for (int step = 0; step < NSTEP; ++step) {
    const int k0 = step * 64;
    int srcA, srcB;
    if (TRIPLE) {
      srcA = (k0 < 2048) ? k0 : k0 - 2048;
      srcB = (k0 < 1024) ? k0 : k0 - 1024;
    } else { srcA = k0; srcB = k0; }
    __syncthreads();
    #pragma unroll
    for (int i = 0; i < 4; ++i) {
      const int row = i * 32 + srow;
      const int u = su ^ (row & 7);
      gld16(A + (long long)(bm0 + row) * KA + srcA + u * 8,
            smem + i * 4096 + wv * 1024);
      gld16(W + (long long)(bn0 + row) * KW + srcB + u * 8,
            smem + 16384 + i * 4096 + wv * 1024);
    }
    asm volatile("s_waitcnt vmcnt(0)" ::: "memory");
    __syncthreads();
    #pragma unroll
    for (int h = 0; h < 2; ++h) {
      bf16x8 af[4], bfr[4];
      #pragma unroll
      for (int i = 0; i < 4; ++i) {
        const int row = rAc + i * 16 + lrow;
        const int u = (h * 4 + lk) ^ (row & 7);
        af[i] = *(const bf16x8*)(smem + row * 128 + u * 16);
      }
      #pragma unroll
      for (int j = 0; j < 4; ++j) {
        const int row = rBc + j * 16 + lrow;
        const int u = (h * 4 + lk) ^ (row & 7);
        bfr[j] = *(const bf16x8*)(smem + 16384 + row * 128 + u * 16);
      }
      #pragma unroll
      for (int i = 0; i < 4; ++i)
        #pragma unroll
        for (int j = 0; j < 4; ++j)
          acc[i][j] = __builtin_amdgcn_mfma_f32_16x16x32_bf16(
              af[i], bfr[j], acc[i][j], 0, 0, 0);
    }
  }
  const int rg = (lane >> 4) * 4;
  #pragma unroll
  for (int j = 0; j < 4; ++j) {
    const int col = bn0 + rBc + j * 16 + (lane & 15);
    const float bj = bp[col];
    #pragma unroll
    for (int i = 0; i < 4; ++i) {
      const int rbase = bm0 + rAc + i * 16 + rg;
      if constexpr (EPI == 0) {
        #pragma unroll
        for (int r = 0; r < 4; ++r)
          C[(long long)(rbase + r) * 1024 + col] = acc[i][j][r] + bj;
      } else {
        const int hh = col >> 6, e = col & 63;
        const int b = rbase >> 11;
        if (z < 2) {
          const int sbase = rbase & 2047;
          ushort* dst = pairout + (long long)z * 8388608 +
                        ((long long)(b * 16 + hh) * 2048 + sbase) * 128 + e;
          #pragma unroll
          for (int r = 0; r < 4; ++r) {
            float val = acc[i][j][r] + bj;
            ushort vh = f2bf(val);
            dst[r * 128] = vh;
            dst[r * 128 + 64] = f2bf(val - bf2f(vh));
          }
        } else {
          const int tb = rbase & 2047;
          ushort4 hi4, lo4;
          ushort* hp = (ushort*)&hi4; ushort* lp = (ushort*)&lo4;
          #pragma unroll
          for (int r = 0; r < 4; ++r) {
            float val = acc[i][j][r] + bj;
            ushort vh = f2bf(val);
            hp[r] = vh;
            lp[r] = f2bf(val - bf2f(vh));
          }
          ushort* vdst = pairout + 2ll * 8388608 +
                         (long long)(b * 16 + hh) * 262144 +
                         (long long)e * 2048 + tb;
          *(ushort4*)vdst = hi4;
          *(ushort4*)(vdst + 131072) = lo4;
        }
      }
    }
  }
}

// =====================================================================
// Suffix sums over t from vtp pairs: vsuf[bh*64+e][t] = sum_{t'>=t} v
// =====================================================================
__global__ __launch_bounds__(256) void suffix_kernel(const ushort* __restrict__ vtp,
                                                     float* __restrict__ vsuf)
{
  const int R = blockIdx.x;        // bh*64+e
  const int bh = R >> 6, e = R & 63;
  const ushort* hi = vtp + (long long)bh * 262144 + (long long)e * 2048;
  const ushort* lo = hi + 131072;
  const int tid = threadIdx.x;
  ushort4 h0 = *(const ushort4*)(hi + tid * 8);
  ushort4 h1 = *(const ushort4*)(hi + tid * 8 + 4);
  ushort4 l0 = *(const ushort4*)(lo + tid * 8);
  ushort4 l1 = *(const ushort4*)(lo + tid * 8 + 4);
  float v[8];
  v[0] = bf2f(h0.x) + bf2f(l0.x); v[1] = bf2f(h0.y) + bf2f(l0.y);
  v[2] = bf2f(h0.z) + bf2f(l0.z); v[3] = bf2f(h0.w) + bf2f(l0.w);
  v[4] = bf2f(h1.x) + bf2f(l1.x); v[5] = bf2f(h1.y) + bf2f(l1.y);
  v[6] = bf2f(h1.z) + bf2f(l1.z); v[7] = bf2f(h1.w) + bf2f(l1.w);
  float s = 0.f;
  #pragma unroll
  for (int x = 0; x < 8; ++x) s += v[x];
  __shared__ float ss[256];
  ss[tid] = s;
  __syncthreads();
  // Hillis-Steele inclusive suffix scan
  for (int off = 1; off < 256; off <<= 1) {
    float t = (tid + off < 256) ? ss[tid + off] : 0.f;
    __syncthreads();
    ss[tid] += t;
    __syncthreads();
  }
  float acc = (tid < 255) ? ss[tid + 1] : 0.f;   // sum over threads > tid
  float out[8];
  for (int x = 7; x >= 0; --x) { acc += v[x]; out[x] = acc; }
  #pragma unroll
  for (int x = 0; x < 8; ++x)
    vsuf[(long long)R * 2048 + tid * 8 + x] = out[x];
}

// =====================================================================
// MFMA attention. 64x64 Q-tile per block, 4 waves each owning a 16-row
// strip. Split-bf16 (3-term) for both QK^T and PV. Masked-zero softmax:
//   out[s] = (sum_{t<=s} e^{qk/32} v_t + vsuf[s+1]) / (l + (S-1-s))
// =====================================================================
__global__ __launch_bounds__(256) void attn_mfma(
    const ushort* __restrict__ qp, const ushort* __restrict__ kp,
    const ushort* __restrict__ vtp, const float* __restrict__ vsuf,
    float* __restrict__ hid)
{
  const int bh = blockIdx.y;
  const int s0 = (int)(gridDim.x - 1 - blockIdx.x) * 64;  // heavy first
  const int tid = threadIdx.x;
  const int lane = tid & 63;
  const int wv = tid >> 6;
  const int g = lane >> 4, c = lane & 15;

  __shared__ char smem[66944] __attribute__((aligned(16)));
  ushort* qs = (ushort*)smem;                    // [64 s][16 units of 16B]
  ushort* ks = (ushort*)(smem + 16384);
  ushort* vt = (ushort*)(smem + 32768);          // [2 sec][64 e][8 units]
  float*  wl = (float*)(smem + 49152);           // [64][68] f32

  const ushort* qbase = qp + (long long)bh * 2048 * 128;
  const ushort* kbase = kp + (long long)bh * 2048 * 128;
  const ushort* vbase = vtp + (long long)bh * 262144;

  // stage q tile once
  #pragma unroll
  for (int i = 0; i < 4; ++i) {
    const int L = i * 256 + tid;
    const int row = L >> 4, u = L & 15;
    const int us = u ^ (row & 15);
    gld16(qbase + (long long)(s0 + row) * 128 + us * 8,
          smem + i * 4096 + wv * 1024);
  }

  f32x4 oacc[4] = {};
  float l_acc[4] = {};

  for (int t0 = 0; t0 <= s0; t0 += 64) {
    __syncthreads();                 // prev PV done (covers qs first iter)
    #pragma unroll
    for (int i = 0; i < 4; ++i) {    // K tile
      const int L = i * 256 + tid;
      const int row = L >> 4, u = L & 15;
      const int us = u ^ (row & 15);
      gld16(kbase + (long long)(t0 + row) * 128 + us * 8,
            smem + 16384 + i * 4096 + wv * 1024);
    }
    #pragma unroll
    for (int i = 0; i < 4; ++i) {    // V tile (transposed layout)
      const int L = i * 256 + tid;
      const int sec = L >> 9, row = (L >> 3) & 63, u = L & 7;
      const int us = u ^ (row & 7);
      gld16(vbase + (long long)sec * 131072 + (long long)row * 2048 + t0 + us * 8,
            smem + 32768 + i * 4096 + wv * 1024);
    }
    asm volatile("s_waitcnt vmcnt(0)" ::: "memory");
    __syncthreads();

    // ---- QK^T (3-term split) ----
    f32x4 acc[4] = {};
    #pragma unroll
    for (int h = 0; h < 2; ++h) {
      const int qrow = wv * 16 + c;
      bf16x8 qh = *(const bf16x8*)(qs + qrow * 128 + (((h * 4 + g) ^ (qrow & 15)) * 8));
      bf16x8 ql = *(const bf16x8*)(qs + qrow * 128 + (((8 + h * 4 + g) ^ (qrow & 15)) * 8));
      #pragma unroll
      for (int j = 0; j < 4; ++j) {
        const int krow = j * 16 + c;
        bf16x8 kh = *(const bf16x8*)(ks + krow * 128 + (((h * 4 + g) ^ (krow & 15)) * 8));
        bf16x8 kl = *(const bf16x8*)(ks + krow * 128 + (((8 + h * 4 + g) ^ (krow & 15)) * 8));
        acc[j] = __builtin_amdgcn_mfma_f32_16x16x32_bf16(qh, kh, acc[j], 0, 0, 0);
        acc[j] = __builtin_amdgcn_mfma_f32_16x16x32_bf16(ql, kh, acc[j], 0, 0, 0);
        acc[j] = __builtin_amdgcn_mfma_f32_16x16x32_bf16(qh, kl, acc[j], 0, 0, 0);
      }
    }

    // ---- mask + exp + row-sum + stash to LDS ----
    float prt[4] = {0.f, 0.f, 0.f, 0.f};
    #pragma unroll
    for (int j = 0; j < 4; ++j) {
      #pragma unroll
      for (int r = 0; r < 4; ++r) {
        const int sg = s0 + wv * 16 + 4 * g + r;
        const int tg = t0 + j * 16 + c;
        const float w = (tg <= sg) ? __expf(acc[j][r] * INV_SQRT_D) : 0.f;
        wl[(wv * 16 + 4 * g + r) * 68 + j * 16 + c] = w;
        prt[r] += w;
      }
    }
    #pragma unroll
    for (int off = 1; off < 16; off <<= 1)
      #pragma unroll
      for (int r = 0; r < 4; ++r) prt[r] += __shfl_xor(prt[r], off);
    #pragma unroll
    for (int r = 0; r < 4; ++r) l_acc[r] += prt[r];

    __syncthreads();                 // wl visible

    // ---- PV (3-term split) ----
    #pragma unroll
    for (int h = 0; h < 2; ++h) {
      const int wrow = wv * 16 + c;
      const float4 w0 = *(const float4*)&wl[wrow * 68 + h * 32 + g * 8];
      const float4 w1 = *(const float4*)&wl[wrow * 68 + h * 32 + g * 8 + 4];
      const float wf[8] = {w0.x, w0.y, w0.z, w0.w, w1.x, w1.y, w1.z, w1.w};
      bf16x8 wh, wlo;
      #pragma unroll
      for (int x = 0; x < 8; ++x) {
        __bf16 hh = (__bf16)wf[x];
        wh[x] = hh;
        wlo[x] = (__bf16)(wf[x] - (float)hh);
      }
      #pragma unroll
      for (int j = 0; j < 4; ++j) {
        const int vrow = j * 16 + c;
        bf16x8 vh = *(const bf16x8*)(vt + vrow * 64 + (((h * 4 + g) ^ (vrow & 7)) * 8));
        bf16x8 vl = *(const bf16x8*)(vt + 4096 + vrow * 64 + (((h * 4 + g) ^ (vrow & 7)) * 8));
        oacc[j] = __builtin_amdgcn_mfma_f32_16x16x32_bf16(wh, vh, oacc[j], 0, 0, 0);
        oacc[j] = __builtin_amdgcn_mfma_f32_16x16x32_bf16(wlo, vh, oacc[j], 0, 0, 0);
        oacc[j] = __builtin_amdgcn_mfma_f32_16x16x32_bf16(wh, vl, oacc[j], 0, 0, 0);
      }
    }
  }

  // ---- epilogue ----
  const int b = bh >> 4, hh = bh & 15;
  #pragma unroll
  for (int r = 0; r < 4; ++r) {
    const int sg = s0 + wv * 16 + 4 * g + r;
    const float denom = l_acc[r] + (float)(S - 1 - sg);
    #pragma unroll
    for (int j = 0; j < 4; ++j) {
      const int e = j * 16 + c;
      const float suf = (sg + 1 < S) ? vsuf[((long long)bh * 64 + e) * 2048 + sg + 1] : 0.f;
      hid[(long long)(b * S + sg) * 1024 + hh * 64 + e] = (oacc[j][r] + suf) / denom;
    }
  }
}

// =====================================================================
// Router: 4 tokens per block (one per wave), vectorized.
// =====================================================================
__global__ __launch_bounds__(256) void router_kernel(
    const float* __restrict__ x, const float* __restrict__ Wsw,
    const float* __restrict__ bsw, int* __restrict__ routes,
    float* __restrict__ rprob)
{
  const int w = threadIdx.x >> 6, lane = threadIdx.x & 63;
  const int i = blockIdx.x * 4 + w;
  float p[E] = {};
  const float4* xr = (const float4*)(x + (long long)i * D);
  #pragma unroll
  for (int t = 0; t < 4; ++t) {
    float4 xv = xr[lane + 64 * t];
    #pragma unroll
    for (int e = 0; e < E; ++e) {
      float4 wv = ((const float4*)(Wsw + e * D))[lane + 64 * t];
      p[e] += xv.x * wv.x + xv.y * wv.y + xv.z * wv.z + xv.w * wv.w;
    }
  }
  #pragma unroll
  for (int off = 32; off; off >>= 1)
    #pragma unroll
    for (int e = 0; e < E; ++e) p[e] += __shfl_xor(p[e], off);
  if (lane == 0) {
    float m = -1e30f; int arg = 0;
    #pragma unroll
    for (int e = 0; e < E; ++e) {
      float l = p[e] + bsw[e];
      if (l > m) { m = l; arg = e; }
      p[e] = l;
    }
    float sum = 0.f;
    #pragma unroll
    for (int e = 0; e < E; ++e) sum += __expf(p[e] - m);
    routes[i] = arg;
    rprob[i] = 1.f / sum;
  }
}

// =====================================================================
// Sequential-order capacity scan. slot = route*ECAP + pos (kept) else -1.
// =====================================================================
__global__ __launch_bounds__(256) void scan_kernel(const int* __restrict__ routes,
                                                   int* __restrict__ slot)
{
  __shared__ int hist[256][E];
  const int tid = threadIdx.x;
  const int per = N / 256;
  int cnt[E] = {};
  for (int j = 0; j < per; ++j) cnt[routes[tid * per + j]]++;
  #pragma unroll
  for (int e = 0; e < E; ++e) hist[tid][e] = cnt[e];
  __syncthreads();
  if (tid < E) {
    int run = 0;
    for (int t = 0; t < 256; ++t) { int tmp = hist[t][tid]; hist[t][tid] = run; run += tmp; }
  }
  __syncthreads();
  int run[E];
  #pragma unroll
  for (int e = 0; e < E; ++e) run[e] = hist[tid][e];
  for (int j = 0; j < per; ++j) {
    int i = tid * per + j;
    int r = routes[i];
    int pos = run[r]++;
    slot[i] = (pos < CAP) ? r * ECAP + pos : -1;
  }
}

// =====================================================================
// Dispatch: scatter kept tokens (fp32 -> bf16) into expert_in[slot]
// =====================================================================
__global__ __launch_bounds__(256) void dispatch_kernel(
    const float* __restrict__ x, const int* __restrict__ slot,
    ushort* __restrict__ expert_in)
{
  const int i = blockIdx.x;
  const int sl = slot[i];
  if (sl < 0) return;
  float4 xv = ((const float4*)&x[(long long)i * D])[threadIdx.x];
  ushort4 o;
  o.x = f2bf(xv.x); o.y = f2bf(xv.y); o.z = f2bf(xv.z); o.w = f2bf(xv.w);
  ((ushort4*)&expert_in[(long long)sl * D])[threadIdx.x] = o;
}

// =====================================================================
// Finalize: gather/passthrough, *route_prob, +embed, LayerNorm.
// =====================================================================
__global__ __launch_bounds__(256) void finalize_kernel(
    const float* __restrict__ x, const float* __restrict__ eout,
    const int* __restrict__ slot, const float* __restrict__ rprob,
    const float* __restrict__ embed, const float* __restrict__ gamma,
    const float* __restrict__ beta, float* __restrict__ out)
{
  const int i = blockIdx.x;
  const int tid = threadIdx.x;
  const int sl = slot[i];
  const float rp = rprob[i];
  const float4* src = (sl >= 0) ? (const float4*)&eout[(long long)sl * D]
                                : (const float4*)&x[(long long)i * D];
  float4 yv = src[tid];
  float4 ev = ((const float4*)&embed[(long long)i * D])[tid];
  float v0 = yv.x * rp + ev.x;
  float v1 = yv.y * rp + ev.y;
  float v2 = yv.z * rp + ev.z;
  float v3 = yv.w * rp + ev.w;
  float s1 = v0 + v1 + v2 + v3;
  float s2 = v0*v0 + v1*v1 + v2*v2 + v3*v3;
  #pragma unroll
  for (int off = 32; off; off >>= 1) {
    s1 += __shfl_xor(s1, off);
    s2 += __shfl_xor(s2, off);
  }
  __shared__ float wsum[4], wsq[4];
  const int wid = tid >> 6, lid = tid & 63;
  if (lid == 0) { wsum[wid] = s1; wsq[wid] = s2; }
  __syncthreads();
  float tot  = wsum[0] + wsum[1] + wsum[2] + wsum[3];
  float tot2 = wsq[0] + wsq[1] + wsq[2] + wsq[3];
  const float mean = tot * (1.f / D);
  const float var = tot2 * (1.f / D) - mean * mean;
  const float rstd = rsqrtf(var + 1e-5f);
  float4 gv = ((const float4*)gamma)[tid];
  float4 bv = ((const float4*)beta)[tid];
  float4 ov;
  ov.x = (v0 - mean) * rstd * gv.x + bv.x;
  ov.y = (v1 - mean) * rstd * gv.y + bv.y;
  ov.z = (v2 - mean) * rstd * gv.z + bv.z;
  ov.w = (v3 - mean) * rstd * gv.w + bv.w;
  ((float4*)&out[(long long)i * D])[tid] = ov;
}

// =====================================================================
extern "C" void kernel_launch(void* const* d_in, const int* in_sizes, int n_in,
                              void* d_out, int out_size, void* d_ws, size_t ws_size,
                              hipStream_t stream) {
  const float* embed = (const float*)d_in[0];
  const float* Wq = (const float*)d_in[1];
  const float* bq = (const float*)d_in[2];
  const float* Wk = (const float*)d_in[3];
  const float* bk = (const float*)d_in[4];
  const float* Wv = (const float*)d_in[5];
  const float* bv = (const float*)d_in[6];
  const float* We = (const float*)d_in[7];
  const float* be = (const float*)d_in[8];
  const float* Wsw = (const float*)d_in[9];
  const float* bsw = (const float*)d_in[10];
  const float* gamma = (const float*)d_in[11];
  const float* beta = (const float*)d_in[12];
  float* out = (float*)d_out;

  // Workspace layout (byte offsets), lifetime-aliased. Peak ~96.6MB.
  char* base = (char*)d_ws;
  ushort* epair      = (ushort*)base;                    // 16.8MB (GEMM in)
  float*  hid        = (float*)base;                     //   reuse after GEMM
  ushort* wpair      = (ushort*)(base + 16777216);       // 12.6MB (GEMM in)
  ushort* expert_in  = (ushort*)(base + 16777216);       //   reuse (10.5MB)
  ushort* pairs      = (ushort*)(base + 29360128);       // qp|kp|vtp 50.3MB
  float*  expert_out = (float*)(base + 29360128);        //   reuse (21MB)
  ushort* qp  = pairs;
  ushort* kp  = pairs + 8388608;
  ushort* vtp = pairs + 2 * 8388608;
  float*  vsuf = (float*)(base + 79691776);              // 16.8MB
  ushort* webf = (ushort*)(base + 79691776);             //   reuse after attn
  int*    routes = (int*)(base + 96468992);
  int*    slot   = routes + N;
  float*  rprob  = (float*)(slot + N);

  // 1. conversions: embed & Wq/Wk/Wv -> hi/lo pair arrays
  cvt_pair<<<N * D / 1024, 256, 0, stream>>>(embed, epair);
  cvt_pair<<<D * D / 1024, 256, 0, stream>>>(Wq, wpair + 0ll * D * 2048);
  cvt_pair<<<D * D / 1024, 256, 0, stream>>>(Wk, wpair + 1ll * D * 2048);
  cvt_pair<<<D * D / 1024, 256, 0, stream>>>(Wv, wpair + 2ll * D * 2048);
  // 2. QKV projection (split-bf16, K'=3072) -> attention-layout pairs
  mfma_gemm<true, 1><<<dim3(8, 32, 3), 256, 0, stream>>>(
      epair, wpair, bq, bk, bv, nullptr, pairs,
      0, (long long)D * 2048, 0, 0, 1);
  // 3. suffix sums of v (from vtp pairs)
  suffix_kernel<<<B * H * 64, 256, 0, stream>>>(vtp, vsuf);
  // 4. MFMA attention -> hiddens
  attn_mfma<<<dim3(S / 64, B * H), 256, 0, stream>>>(qp, kp, vtp, vsuf, hid);
  // 5. router
  router_kernel<<<N / 4, 256, 0, stream>>>(hid, Wsw, bsw, routes, rprob);
  // 6. capacity scan
  scan_kernel<<<1, 256, 0, stream>>>(routes, slot);
  // 7. We -> bf16 (overwrites vsuf; after attention)
  cvt_plain<<<(int)((long long)E * D * D / 1024), 256, 0, stream>>>(We, webf);
  // 8. dispatch tokens -> expert_in (bf16)
  dispatch_kernel<<<N, 256, 0, stream>>>(hid, slot, expert_in);
  // 9. expert GEMMs: plain bf16 (K=1024), M padded to 640
  mfma_gemm<false, 0><<<dim3(8, ECAP / 128, E), 256, 0, stream>>>(
      expert_in, webf, be, nullptr, nullptr, expert_out, nullptr,
      (long long)ECAP * D, (long long)D * D, (long long)ECAP * D,
      (long long)D, 0);
  // 10. gather + combine + residual + LayerNorm
  finalize_kernel<<<N, 256, 0, stream>>>(hid, expert_out, slot, rprob,
                                         embed, gamma, beta, out);
}

// Round 5
// 469.288 us; speedup vs baseline: 3.5578x; 1.0189x over previous
//
#include <hip/hip_runtime.h>

// Problem constants (match reference)
constexpr int B = 2, S = 2048, D = 1024, H = 16, E = 8, DH = 64;
constexpr int N = B * S;          // 4096 tokens
constexpr int CAP = 614;          // int(1.2 * N / E) -- capacity check
constexpr int ECAP = 640;         // padded rows per expert (5 * 128 tiles)
constexpr float INV_SQRT_D = 0.03125f;   // 1/sqrt(1024)
constexpr int ATTN_LDS = 133120;  // q32K + K 2x16K + V 2x16K + wl 34.8K

typedef __bf16 bf16x8 __attribute__((ext_vector_type(8)));
typedef float f32x4 __attribute__((ext_vector_type(4)));

__device__ __forceinline__ ushort f2bf(float x) {
  __bf16 h = (__bf16)x;
  return __builtin_bit_cast(unsigned short, h);
}
__device__ __forceinline__ float bf2f(ushort u) {
  __bf16 h = __builtin_bit_cast(__bf16, u);
  return (float)h;
}
// 16B direct global->LDS. LDS dest is wave-uniform base (+ lane*16 by HW).
__device__ __forceinline__ void gld16(const void* g, void* l) {
  __builtin_amdgcn_global_load_lds(
      (const __attribute__((address_space(1))) unsigned int*)g,
      (__attribute__((address_space(3))) unsigned int*)l, 16, 0, 0);
}

// =====================================================================
// fp32 -> bf16 hi/lo pair. in [rows][1024] f32, out [rows][2048] bf16
// =====================================================================
__global__ __launch_bounds__(256) void cvt_pair(const float* __restrict__ in,
                                                ushort* __restrict__ out)
{
  const long long idx4 = (long long)blockIdx.x * 256 + threadIdx.x;  // float4 idx
  const float4 xv = ((const float4*)in)[idx4];
  const long long row = idx4 >> 8;            // 256 float4 per row
  const int col = (int)((idx4 & 255) << 2);
  float xs[4] = {xv.x, xv.y, xv.z, xv.w};
  ushort4 hi, lo;
  ushort* hp = (ushort*)&hi; ushort* lp = (ushort*)&lo;
  #pragma unroll
  for (int c = 0; c < 4; ++c) {
    ushort h = f2bf(xs[c]);
    hp[c] = h;
    lp[c] = f2bf(xs[c] - bf2f(h));
  }
  *(ushort4*)&out[row * 2048 + col] = hi;
  *(ushort4*)&out[row * 2048 + 1024 + col] = lo;
}

// plain fp32 -> bf16, flat
__global__ __launch_bounds__(256) void cvt_plain(const float* __restrict__ in,
                                                 ushort* __restrict__ out)
{
  const long long idx4 = (long long)blockIdx.x * 256 + threadIdx.x;
  const float4 xv = ((const float4*)in)[idx4];
  ushort4 o;
  o.x = f2bf(xv.x); o.y = f2bf(xv.y); o.z = f2bf(xv.z); o.w = f2bf(xv.w);
  *(ushort4*)&out[idx4 * 4] = o;
}

// =====================================================================
// bf16 MFMA GEMM.  TRIPLE: hi/lo split, logical K'=3072.
// EPI=0: C f32 [M][1024] + bias.  EPI=1 (QKV): write bf16 hi/lo pairs:
//   z=0/1 (q/k): pairout[z][bh][s][128]  (cols 0-63 hi, 64-127 lo)
//   z=2   (v)  : vtp[bh][sec][e][2048]   (transposed, sec=hi/lo)
// =====================================================================
template <bool TRIPLE, int EPI>
__global__ __launch_bounds__(256) void mfma_gemm(
    const ushort* __restrict__ A, const ushort* __restrict__ W,
    const float* __restrict__ b0, const float* __restrict__ b1,
    const float* __restrict__ b2, float* __restrict__ C,
    ushort* __restrict__ pairout,
    long long strideA, long long strideW, long long strideC,
    long long biasStride, int biasSel)
{
  constexpr int KA = TRIPLE ? 2048 : 1024;
  constexpr int KW = TRIPLE ? 2048 : 1024;
  constexpr int NSTEP = TRIPLE ? 48 : 16;
  const int z = blockIdx.z;
  A += (long long)z * strideA;
  W += (long long)z * strideW;
  C += (long long)z * strideC;
  const float* bp = biasSel ? (z == 0 ? b0 : (z == 1 ? b1 : b2))
                            : b0 + (long long)z * biasStride;

  __shared__ char smem[32768] __attribute__((aligned(128)));
  const int tid = threadIdx.x;
  const int lane = tid & 63;
  const int lrow = lane & 15;
  const int lk = lane >> 4;
  const int wv = tid >> 6;
  const int rAc = (wv >> 1) * 64;
  const int rBc = (wv & 1) * 64;
  const int bm0 = blockIdx.y * 128;
  const int bn0 = blockIdx.x * 128;
  const int srow = tid >> 3;
  const int su = tid & 7;

  f32x4 acc[4][4] = {};

  for (int step = 0; step < NSTEP; ++step) {
    const int k0 = step * 64;
    int srcA, srcB;
    if (TRIPLE) {
      srcA = (k0 < 2048) ? k0 : k0 - 2048;
      srcB = (k0 < 1024) ? k0 : k0 - 1024;
    } else { srcA = k0; srcB = k0; }
    __syncthreads();
    #pragma unroll
    for (int i = 0; i < 4; ++i) {
      const int row = i * 32 + srow;
      const int u = su ^ (row & 7);
      gld16(A + (long long)(bm0 + row) * KA + srcA + u * 8,
            smem + i * 4096 + wv * 1024);
      gld16(W + (long long)(bn0 + row) * KW + srcB + u * 8,
            smem + 16384 + i * 4096 + wv * 1024);
    }
    asm volatile("s_waitcnt vmcnt(0)" ::: "memory");
    __syncthreads();
    #pragma unroll
    for (int h = 0; h < 2; ++h) {
      bf16x8 af[4], bfr[4];
      #pragma unroll
      for (int i = 0; i < 4; ++i) {
        const int row = rAc + i * 16 + lrow;
        const int u = (h * 4 + lk) ^ (row & 7);
        af[i] = *(const bf16x8*)(smem + row * 128 + u * 16);
      }
      #pragma unroll
      for (int j = 0; j < 4; ++j) {
        const int row = rBc + j * 16 + lrow;
        const int u = (h * 4 + lk) ^ (row & 7);
        bfr[j] = *(const bf16x8*)(smem + 16384 + row * 128 + u * 16);
      }
      #pragma unroll
      for (int i = 0; i < 4; ++i)
        #pragma unroll
        for (int j = 0; j < 4; ++j)
          acc[i][j] = __builtin_amdgcn_mfma_f32_16x16x32_bf16(
              af[i], bfr[j], acc[i][j], 0, 0, 0);
    }
  }
  const int rg = (lane >> 4) * 4;
  #pragma unroll
  for (int j = 0; j < 4; ++j) {
    const int col = bn0 + rBc + j * 16 + (lane & 15);
    const float bj = bp[col];
    #pragma unroll
    for (int i = 0; i < 4; ++i) {
      const int rbase = bm0 + rAc + i * 16 + rg;
      if constexpr (EPI == 0) {
        #pragma unroll
        for (int r = 0; r < 4; ++r)
          C[(long long)(rbase + r) * 1024 + col] = acc[i][j][r] + bj;
      } else {
        const int hh = col >> 6, e = col & 63;
        const int b = rbase >> 11;
        if (z < 2) {
          const int sbase = rbase & 2047;
          ushort* dst = pairout + (long long)z * 8388608 +
                        ((long long)(b * 16 + hh) * 2048 + sbase) * 128 + e;
          #pragma unroll
          for (int r = 0; r < 4; ++r) {
            float val = acc[i][j][r] + bj;
            ushort vh = f2bf(val);
            dst[r * 128] = vh;
            dst[r * 128 + 64] = f2bf(val - bf2f(vh));
          }
        } else {
          const int tb = rbase & 2047;
          ushort4 hi4, lo4;
          ushort* hp = (ushort*)&hi4; ushort* lp = (ushort*)&lo4;
          #pragma unroll
          for (int r = 0; r < 4; ++r) {
            float val = acc[i][j][r] + bj;
            ushort vh = f2bf(val);
            hp[r] = vh;
            lp[r] = f2bf(val - bf2f(vh));
          }
          ushort* vdst = pairout + 2ll * 8388608 +
                         (long long)(b * 16 + hh) * 262144 +
                         (long long)e * 2048 + tb;
          *(ushort4*)vdst = hi4;
          *(ushort4*)(vdst + 131072) = lo4;
        }
      }
    }
  }
}

// =====================================================================
// Suffix sums over t from vtp pairs: vsuf[bh*64+e][t] = sum_{t'>=t} v
// =====================================================================
__global__ __launch_bounds__(256) void suffix_kernel(const ushort* __restrict__ vtp,
                                                     float* __restrict__ vsuf)
{
  const int R = blockIdx.x;        // bh*64+e
  const int bh = R >> 6, e = R & 63;
  const ushort* hi = vtp + (long long)bh * 262144 + (long long)e * 2048;
  const ushort* lo = hi + 131072;
  const int tid = threadIdx.x;
  ushort4 h0 = *(const ushort4*)(hi + tid * 8);
  ushort4 h1 = *(const ushort4*)(hi + tid * 8 + 4);
  ushort4 l0 = *(const ushort4*)(lo + tid * 8);
  ushort4 l1 = *(const ushort4*)(lo + tid * 8 + 4);
  float v[8];
  v[0] = bf2f(h0.x) + bf2f(l0.x); v[1] = bf2f(h0.y) + bf2f(l0.y);
  v[2] = bf2f(h0.z) + bf2f(l0.z); v[3] = bf2f(h0.w) + bf2f(l0.w);
  v[4] = bf2f(h1.x) + bf2f(l1.x); v[5] = bf2f(h1.y) + bf2f(l1.y);
  v[6] = bf2f(h1.z) + bf2f(l1.z); v[7] = bf2f(h1.w) + bf2f(l1.w);
  float s = 0.f;
  #pragma unroll
  for (int x = 0; x < 8; ++x) s += v[x];
  __shared__ float ss[256];
  ss[tid] = s;
  __syncthreads();
  // Hillis-Steele inclusive suffix scan
  for (int off = 1; off < 256; off <<= 1) {
    float t = (tid + off < 256) ? ss[tid + off] : 0.f;
    __syncthreads();
    ss[tid] += t;
    __syncthreads();
  }
  float acc = (tid < 255) ? ss[tid + 1] : 0.f;   // sum over threads > tid
  float out[8];
  for (int x = 7; x >= 0; --x) { acc += v[x]; out[x] = acc; }
  #pragma unroll
  for (int x = 0; x < 8; ++x)
    vsuf[(long long)R * 2048 + tid * 8 + x] = out[x];
}

// =====================================================================
// MFMA attention, v2: 128-row Q-tile, 8 waves, double-buffered K/V with
// counted vmcnt + raw barriers (2-phase recipe). Split-bf16 3-term.
//   out[s] = (sum_{t<=s} e^{qk/32} v_t + vsuf[s+1]) / (l + (S-1-s))
// LDS: qs 32K | K dbuf 2x16K | V dbuf 2x16K | wl 128x68 f32 (34.8K)
// =====================================================================
__device__ __forceinline__ void attn_stage_kv(
    const ushort* kbase, const ushort* vbase, int t0,
    char* kdst, char* vdst, int tid, int wv)
{
  #pragma unroll
  for (int i = 0; i < 2; ++i) {     // K: 64 rows x 16 units
    const int L = i * 512 + tid;
    const int row = L >> 4, u = L & 15;
    gld16(kbase + (long long)(t0 + row) * 128 + ((u ^ (row & 15)) * 8),
          kdst + i * 8192 + wv * 1024);
  }
  #pragma unroll
  for (int i = 0; i < 2; ++i) {     // V: 2 sec x 64 e-rows x 8 units
    const int L = i * 512 + tid;
    const int sec = L >> 9, vr = (L >> 3) & 63, u = L & 7;
    gld16(vbase + (long long)sec * 131072 + (long long)vr * 2048 + t0 +
              ((u ^ (vr & 7)) * 8),
          vdst + i * 8192 + wv * 1024);
  }
}

__global__ __launch_bounds__(512) void attn_mfma(
    const ushort* __restrict__ qp, const ushort* __restrict__ kp,
    const ushort* __restrict__ vtp, const float* __restrict__ vsuf,
    float* __restrict__ hid)
{
  extern __shared__ char smem[];
  const int bh = blockIdx.y;
  const int qi = (int)(gridDim.x - 1 - blockIdx.x);   // heavy blocks first
  const int sB0 = qi * 128;
  const int tid = threadIdx.x;
  const int lane = tid & 63;
  const int wv = tid >> 6;            // 0..7
  const int g = lane >> 4, c = lane & 15;

  ushort* qs = (ushort*)smem;                       // [128 s][16 x 16B]
  char* kbuf0 = smem + 32768;
  char* kbuf1 = smem + 49152;
  char* vbuf0 = smem + 65536;
  char* vbuf1 = smem + 81920;
  float* wl = (float*)(smem + 98304);               // [128][68] f32

  const ushort* qbase = qp + (long long)bh * 2048 * 128;
  const ushort* kbase = kp + (long long)bh * 2048 * 128;
  const ushort* vbase = vtp + (long long)bh * 262144;

  // prologue: stage q (4 issues) + KV tile 0 (4 issues)
  #pragma unroll
  for (int i = 0; i < 4; ++i) {
    const int L = i * 512 + tid;
    const int row = L >> 4, u = L & 15;
    gld16(qbase + (long long)(sB0 + row) * 128 + ((u ^ (row & 15)) * 8),
          smem + i * 8192 + wv * 1024);
  }
  char* kcur = kbuf0; char* knext = kbuf1;
  char* vcur = vbuf0; char* vnext = vbuf1;
  attn_stage_kv(kbase, vbase, 0, kcur, vcur, tid, wv);

  f32x4 oacc[4] = {};
  float l_acc[4] = {};
  const int nt = 2 * qi + 2;
  const int qrow = wv * 16 + c;       // this lane's A-fragment q row

  for (int t = 0; t < nt; ++t) {
    const int t0 = t * 64;
    if (t + 1 < nt) {
      attn_stage_kv(kbase, vbase, t0 + 64, knext, vnext, tid, wv);
      asm volatile("s_waitcnt vmcnt(4)" ::: "memory");  // cur tile landed
    } else {
      asm volatile("s_waitcnt vmcnt(0)" ::: "memory");
    }
    __builtin_amdgcn_s_barrier();     // all waves: cur K/V ready; prev PV done

    const ushort* ks = (const ushort*)kcur;
    const ushort* vt = (const ushort*)vcur;

    // ---- QK^T (3-term split) ----
    f32x4 acc[4] = {};
    #pragma unroll
    for (int h = 0; h < 2; ++h) {
      bf16x8 qh = *(const bf16x8*)(qs + qrow * 128 + (((h * 4 + g) ^ (qrow & 15)) * 8));
      bf16x8 ql = *(const bf16x8*)(qs + qrow * 128 + (((8 + h * 4 + g) ^ (qrow & 15)) * 8));
      #pragma unroll
      for (int j = 0; j < 4; ++j) {
        const int krow = j * 16 + c;
        bf16x8 kh = *(const bf16x8*)(ks + krow * 128 + (((h * 4 + g) ^ (krow & 15)) * 8));
        bf16x8 kl = *(const bf16x8*)(ks + krow * 128 + (((8 + h * 4 + g) ^ (krow & 15)) * 8));
        acc[j] = __builtin_amdgcn_mfma_f32_16x16x32_bf16(qh, kh, acc[j], 0, 0, 0);
        acc[j] = __builtin_amdgcn_mfma_f32_16x16x32_bf16(ql, kh, acc[j], 0, 0, 0);
        acc[j] = __builtin_amdgcn_mfma_f32_16x16x32_bf16(qh, kl, acc[j], 0, 0, 0);
      }
    }

    // ---- mask + exp + row-sum + stash to LDS ----
    float prt[4] = {0.f, 0.f, 0.f, 0.f};
    #pragma unroll
    for (int j = 0; j < 4; ++j) {
      #pragma unroll
      for (int r = 0; r < 4; ++r) {
        const int sg = sB0 + wv * 16 + 4 * g + r;
        const int tg = t0 + j * 16 + c;
        const float w = (tg <= sg) ? __expf(acc[j][r] * INV_SQRT_D) : 0.f;
        wl[(wv * 16 + 4 * g + r) * 68 + j * 16 + c] = w;
        prt[r] += w;
      }
    }
    #pragma unroll
    for (int off = 1; off < 16; off <<= 1)
      #pragma unroll
      for (int r = 0; r < 4; ++r) prt[r] += __shfl_xor(prt[r], off);
    #pragma unroll
    for (int r = 0; r < 4; ++r) l_acc[r] += prt[r];

    asm volatile("s_waitcnt lgkmcnt(0)" ::: "memory");  // wl stores done
    __builtin_amdgcn_s_barrier();                       // wl visible

    // ---- PV (3-term split) ----
    #pragma unroll
    for (int h = 0; h < 2; ++h) {
      const int wrow = wv * 16 + c;
      const float4 w0 = *(const float4*)&wl[wrow * 68 + h * 32 + g * 8];
      const float4 w1 = *(const float4*)&wl[wrow * 68 + h * 32 + g * 8 + 4];
      const float wf[8] = {w0.x, w0.y, w0.z, w0.w, w1.x, w1.y, w1.z, w1.w};
      bf16x8 wh, wlo;
      #pragma unroll
      for (int x = 0; x < 8; ++x) {
        __bf16 hh = (__bf16)wf[x];
        wh[x] = hh;
        wlo[x] = (__bf16)(wf[x] - (float)hh);
      }
      #pragma unroll
      for (int j = 0; j < 4; ++j) {
        const int vrow = j * 16 + c;
        bf16x8 vh = *(const bf16x8*)(vt + vrow * 64 + (((h * 4 + g) ^ (vrow & 7)) * 8));
        bf16x8 vl = *(const bf16x8*)(vt + 4096 + vrow * 64 + (((h * 4 + g) ^ (vrow & 7)) * 8));
        oacc[j] = __builtin_amdgcn_mfma_f32_16x16x32_bf16(wh, vh, oacc[j], 0, 0, 0);
        oacc[j] = __builtin_amdgcn_mfma_f32_16x16x32_bf16(wlo, vh, oacc[j], 0, 0, 0);
        oacc[j] = __builtin_amdgcn_mfma_f32_16x16x32_bf16(wh, vl, oacc[j], 0, 0, 0);
      }
    }
    __builtin_amdgcn_s_barrier();     // done reading cur bufs + wl
    char* tk = kcur; kcur = knext; knext = tk;
    char* tv = vcur; vcur = vnext; vnext = tv;
  }

  // ---- epilogue ----
  const int b = bh >> 4, hh = bh & 15;
  #pragma unroll
  for (int r = 0; r < 4; ++r) {
    const int sg = sB0 + wv * 16 + 4 * g + r;
    const float denom = l_acc[r] + (float)(S - 1 - sg);
    #pragma unroll
    for (int j = 0; j < 4; ++j) {
      const int e = j * 16 + c;
      const float suf = (sg + 1 < S) ? vsuf[((long long)bh * 64 + e) * 2048 + sg + 1] : 0.f;
      hid[(long long)(b * S + sg) * 1024 + hh * 64 + e] = (oacc[j][r] + suf) / denom;
    }
  }
}

// =====================================================================
// Router: 4 tokens per block (one per wave), vectorized.
// =====================================================================
__global__ __launch_bounds__(256) void router_kernel(
    const float* __restrict__ x, const float* __restrict__ Wsw,
    const float* __restrict__ bsw, int* __restrict__ routes,
    float* __restrict__ rprob)
{
  const int w = threadIdx.x >> 6, lane = threadIdx.x & 63;
  const int i = blockIdx.x * 4 + w;
  float p[E] = {};
  const float4* xr = (const float4*)(x + (long long)i * D);
  #pragma unroll
  for (int t = 0; t < 4; ++t) {
    float4 xv = xr[lane + 64 * t];
    #pragma unroll
    for (int e = 0; e < E; ++e) {
      float4 wv = ((const float4*)(Wsw + e * D))[lane + 64 * t];
      p[e] += xv.x * wv.x + xv.y * wv.y + xv.z * wv.z + xv.w * wv.w;
    }
  }
  #pragma unroll
  for (int off = 32; off; off >>= 1)
    #pragma unroll
    for (int e = 0; e < E; ++e) p[e] += __shfl_xor(p[e], off);
  if (lane == 0) {
    float m = -1e30f; int arg = 0;
    #pragma unroll
    for (int e = 0; e < E; ++e) {
      float l = p[e] + bsw[e];
      if (l > m) { m = l; arg = e; }
      p[e] = l;
    }
    float sum = 0.f;
    #pragma unroll
    for (int e = 0; e < E; ++e) sum += __expf(p[e] - m);
    routes[i] = arg;
    rprob[i] = 1.f / sum;
  }
}

// =====================================================================
// Sequential-order capacity scan. slot = route*ECAP + pos (kept) else -1.
// =====================================================================
__global__ __launch_bounds__(256) void scan_kernel(const int* __restrict__ routes,
                                                   int* __restrict__ slot)
{
  __shared__ int hist[256][E];
  const int tid = threadIdx.x;
  const int per = N / 256;
  int cnt[E] = {};
  for (int j = 0; j < per; ++j) cnt[routes[tid * per + j]]++;
  #pragma unroll
  for (int e = 0; e < E; ++e) hist[tid][e] = cnt[e];
  __syncthreads();
  if (tid < E) {
    int run = 0;
    for (int t = 0; t < 256; ++t) { int tmp = hist[t][tid]; hist[t][tid] = run; run += tmp; }
  }
  __syncthreads();
  int run[E];
  #pragma unroll
  for (int e = 0; e < E; ++e) run[e] = hist[tid][e];
  for (int j = 0; j < per; ++j) {
    int i = tid * per + j;
    int r = routes[i];
    int pos = run[r]++;
    slot[i] = (pos < CAP) ? r * ECAP + pos : -1;
  }
}

// =====================================================================
// Dispatch: scatter kept tokens (fp32 -> bf16) into expert_in[slot]
// =====================================================================
__global__ __launch_bounds__(256) void dispatch_kernel(
    const float* __restrict__ x, const int* __restrict__ slot,
    ushort* __restrict__ expert_in)
{
  const int i = blockIdx.x;
  const int sl = slot[i];
  if (sl < 0) return;
  float4 xv = ((const float4*)&x[(long long)i * D])[threadIdx.x];
  ushort4 o;
  o.x = f2bf(xv.x); o.y = f2bf(xv.y); o.z = f2bf(xv.z); o.w = f2bf(xv.w);
  ((ushort4*)&expert_in[(long long)sl * D])[threadIdx.x] = o;
}

// =====================================================================
// Finalize: gather/passthrough, *route_prob, +embed, LayerNorm.
// =====================================================================
__global__ __launch_bounds__(256) void finalize_kernel(
    const float* __restrict__ x, const float* __restrict__ eout,
    const int* __restrict__ slot, const float* __restrict__ rprob,
    const float* __restrict__ embed, const float* __restrict__ gamma,
    const float* __restrict__ beta, float* __restrict__ out)
{
  const int i = blockIdx.x;
  const int tid = threadIdx.x;
  const int sl = slot[i];
  const float rp = rprob[i];
  const float4* src = (sl >= 0) ? (const float4*)&eout[(long long)sl * D]
                                : (const float4*)&x[(long long)i * D];
  float4 yv = src[tid];
  float4 ev = ((const float4*)&embed[(long long)i * D])[tid];
  float v0 = yv.x * rp + ev.x;
  float v1 = yv.y * rp + ev.y;
  float v2 = yv.z * rp + ev.z;
  float v3 = yv.w * rp + ev.w;
  float s1 = v0 + v1 + v2 + v3;
  float s2 = v0*v0 + v1*v1 + v2*v2 + v3*v3;
  #pragma unroll
  for (int off = 32; off; off >>= 1) {
    s1 += __shfl_xor(s1, off);
    s2 += __shfl_xor(s2, off);
  }
  __shared__ float wsum[4], wsq[4];
  const int wid = tid >> 6, lid = tid & 63;
  if (lid == 0) { wsum[wid] = s1; wsq[wid] = s2; }
  __syncthreads();
  float tot  = wsum[0] + wsum[1] + wsum[2] + wsum[3];
  float tot2 = wsq[0] + wsq[1] + wsq[2] + wsq[3];
  const float mean = tot * (1.f / D);
  const float var = tot2 * (1.f / D) - mean * mean;
  const float rstd = rsqrtf(var + 1e-5f);
  float4 gv = ((const float4*)gamma)[tid];
  float4 bv = ((const float4*)beta)[tid];
  float4 ov;
  ov.x = (v0 - mean) * rstd * gv.x + bv.x;
  ov.y = (v1 - mean) * rstd * gv.y + bv.y;
  ov.z = (v2 - mean) * rstd * gv.z + bv.z;
  ov.w = (v3 - mean) * rstd * gv.w + bv.w;
  ((float4*)&out[(long long)i * D])[tid] = ov;
}

// =====================================================================
extern "C" void kernel_launch(void* const* d_in, const int* in_sizes, int n_in,
                              void* d_out, int out_size, void* d_ws, size_t ws_size,
                              hipStream_t stream) {
  const float* embed = (const float*)d_in[0];
  const float* Wq = (const float*)d_in[1];
  const float* bq = (const float*)d_in[2];
  const float* Wk = (const float*)d_in[3];
  const float* bk = (const float*)d_in[4];
  const float* Wv = (const float*)d_in[5];
  const float* bv = (const float*)d_in[6];
  const float* We = (const float*)d_in[7];
  const float* be = (const float*)d_in[8];
  const float* Wsw = (const float*)d_in[9];
  const float* bsw = (const float*)d_in[10];
  const float* gamma = (const float*)d_in[11];
  const float* beta = (const float*)d_in[12];
  float* out = (float*)d_out;

  // Allow >64KB dynamic LDS for attn (host-side, capture-safe, idempotent).
  (void)hipFuncSetAttribute((const void*)attn_mfma,
                            hipFuncAttributeMaxDynamicSharedMemorySize,
                            ATTN_LDS);

  // Workspace layout (byte offsets), lifetime-aliased. Peak ~96.6MB.
  char* base = (char*)d_ws;
  ushort* epair      = (ushort*)base;                    // 16.8MB (GEMM in)
  float*  hid        = (float*)base;                     //   reuse after GEMM
  ushort* wpair      = (ushort*)(base + 16777216);       // 12.6MB (GEMM in)
  ushort* expert_in  = (ushort*)(base + 16777216);       //   reuse (10.5MB)
  ushort* pairs      = (ushort*)(base + 29360128);       // qp|kp|vtp 50.3MB
  float*  expert_out = (float*)(base + 29360128);        //   reuse (21MB)
  ushort* qp  = pairs;
  ushort* kp  = pairs + 8388608;
  ushort* vtp = pairs + 2 * 8388608;
  float*  vsuf = (float*)(base + 79691776);              // 16.8MB
  ushort* webf = (ushort*)(base + 79691776);             //   reuse after attn
  int*    routes = (int*)(base + 96468992);
  int*    slot   = routes + N;
  float*  rprob  = (float*)(slot + N);

  // 1. conversions: embed & Wq/Wk/Wv -> hi/lo pair arrays
  cvt_pair<<<N * D / 1024, 256, 0, stream>>>(embed, epair);
  cvt_pair<<<D * D / 1024, 256, 0, stream>>>(Wq, wpair + 0ll * D * 2048);
  cvt_pair<<<D * D / 1024, 256, 0, stream>>>(Wk, wpair + 1ll * D * 2048);
  cvt_pair<<<D * D / 1024, 256, 0, stream>>>(Wv, wpair + 2ll * D * 2048);
  // 2. QKV projection (split-bf16, K'=3072) -> attention-layout pairs
  mfma_gemm<true, 1><<<dim3(8, 32, 3), 256, 0, stream>>>(
      epair, wpair, bq, bk, bv, nullptr, pairs,
      0, (long long)D * 2048, 0, 0, 1);
  // 3. suffix sums of v (from vtp pairs)
  suffix_kernel<<<B * H * 64, 256, 0, stream>>>(vtp, vsuf);
  // 4. MFMA attention v2 -> hiddens (128-row q tiles, dbuf KV)
  attn_mfma<<<dim3(S / 128, B * H), 512, ATTN_LDS, stream>>>(
      qp, kp, vtp, vsuf, hid);
  // 5. router
  router_kernel<<<N / 4, 256, 0, stream>>>(hid, Wsw, bsw, routes, rprob);
  // 6. capacity scan
  scan_kernel<<<1, 256, 0, stream>>>(routes, slot);
  // 7. We -> bf16 (overwrites vsuf; after attention)
  cvt_plain<<<(int)((long long)E * D * D / 1024), 256, 0, stream>>>(We, webf);
  // 8. dispatch tokens -> expert_in (bf16)
  dispatch_kernel<<<N, 256, 0, stream>>>(hid, slot, expert_in);
  // 9. expert GEMMs: plain bf16 (K=1024), M padded to 640
  mfma_gemm<false, 0><<<dim3(8, ECAP / 128, E), 256, 0, stream>>>(
      expert_in, webf, be, nullptr, nullptr, expert_out, nullptr,
      (long long)ECAP * D, (long long)D * D, (long long)ECAP * D,
      (long long)D, 0);
  // 10. gather + combine + residual + LayerNorm
  finalize_kernel<<<N, 256, 0, stream>>>(hid, expert_out, slot, rprob,
                                         embed, gamma, beta, out);
}

// Round 7
// 404.658 us; speedup vs baseline: 4.1260x; 1.1597x over previous
//
#include <hip/hip_runtime.h>

// Problem constants (match reference)
constexpr int B = 2, S = 2048, D = 1024, H = 16, E = 8, DH = 64;
constexpr int N = B * S;          // 4096 tokens
constexpr int CAP = 614;          // int(1.2 * N / E) -- capacity check
constexpr int ECAP = 640;         // padded rows per expert (5 * 128 tiles)
constexpr float INV_SQRT_D = 0.03125f;   // 1/sqrt(1024)

typedef __bf16 bf16x8 __attribute__((ext_vector_type(8)));
typedef float f32x4 __attribute__((ext_vector_type(4)));
typedef unsigned int u32x4 __attribute__((ext_vector_type(4)));

__device__ __forceinline__ ushort f2bf(float x) {
  __bf16 h = (__bf16)x;
  return __builtin_bit_cast(unsigned short, h);
}
__device__ __forceinline__ float bf2f(ushort u) {
  __bf16 h = __builtin_bit_cast(__bf16, u);
  return (float)h;
}
// 16B direct global->LDS. LDS dest is wave-uniform base (+ lane*16 by HW).
__device__ __forceinline__ void gld16(const void* g, void* l) {
  __builtin_amdgcn_global_load_lds(
      (const __attribute__((address_space(1))) unsigned int*)g,
      (__attribute__((address_space(3))) unsigned int*)l, 16, 0, 0);
}

// =====================================================================
// fp32 -> bf16 hi/lo pair. in [rows][1024] f32, out [rows][2048] bf16
// =====================================================================
__global__ __launch_bounds__(256) void cvt_pair(const float* __restrict__ in,
                                                ushort* __restrict__ out)
{
  const long long idx4 = (long long)blockIdx.x * 256 + threadIdx.x;  // float4 idx
  const float4 xv = ((const float4*)in)[idx4];
  const long long row = idx4 >> 8;            // 256 float4 per row
  const int col = (int)((idx4 & 255) << 2);
  float xs[4] = {xv.x, xv.y, xv.z, xv.w};
  ushort4 hi, lo;
  ushort* hp = (ushort*)&hi; ushort* lp = (ushort*)&lo;
  #pragma unroll
  for (int c = 0; c < 4; ++c) {
    ushort h = f2bf(xs[c]);
    hp[c] = h;
    lp[c] = f2bf(xs[c] - bf2f(h));
  }
  *(ushort4*)&out[row * 2048 + col] = hi;
  *(ushort4*)&out[row * 2048 + 1024 + col] = lo;
}

// plain fp32 -> bf16, flat
__global__ __launch_bounds__(256) void cvt_plain(const float* __restrict__ in,
                                                 ushort* __restrict__ out)
{
  const long long idx4 = (long long)blockIdx.x * 256 + threadIdx.x;
  const float4 xv = ((const float4*)in)[idx4];
  ushort4 o;
  o.x = f2bf(xv.x); o.y = f2bf(xv.y); o.z = f2bf(xv.z); o.w = f2bf(xv.w);
  *(ushort4*)&out[idx4 * 4] = o;
}

// =====================================================================
// QKV GEMM merged over N=3072 (q|k|v). Split-bf16 hi/lo, logical K'=3072
// over pair arrays (hi*hi + lo*hi + hi*lo). 128x128 tile, BK=64, 4 waves.
// Epilogue writes attention-layout bf16 pairs:
//   z=0/1 (q/k): pairout[z][bh][s][128] (cols 0-63 hi, 64-127 lo)
//   z=2   (v)  : vtp[bh][sec][e][2048]  (transposed, sec=hi/lo)
// Chunked XCD swizzle: each XCD works 4 contiguous m-panels.
// =====================================================================
__global__ __launch_bounds__(256) void qkv_gemm(
    const ushort* __restrict__ A, const ushort* __restrict__ Wp,
    const float* __restrict__ bq, const float* __restrict__ bk,
    const float* __restrict__ bv, ushort* __restrict__ pairout)
{
  __shared__ char smem[32768] __attribute__((aligned(128)));
  const int tid = threadIdx.x;
  const int lane = tid & 63;
  const int lrow = lane & 15;
  const int lk = lane >> 4;
  const int wv = tid >> 6;
  const int rAc = (wv >> 1) * 64;
  const int rBc = (wv & 1) * 64;
  const int flat = (int)(blockIdx.y * 24 + blockIdx.x);   // 0..767
  const int swz = (flat & 7) * 96 + (flat >> 3);          // chunked XCD swizzle
  const int bn0 = (swz % 24) * 128;
  const int bm0 = (swz / 24) * 128;
  const int z = bn0 >> 10;                                // 0=q 1=k 2=v (uniform)
  const ushort* Wt = Wp + (long long)z * (1024 * 2048) +
                     (long long)(bn0 & 1023) * 2048;
  const float* bp = (z == 0) ? bq : (z == 1) ? bk : bv;
  const int srow = tid >> 3;
  const int su = tid & 7;

  f32x4 acc[4][4] = {};

  for (int step = 0; step < 48; ++step) {
    const int k0 = step * 64;
    const int srcA = (k0 < 2048) ? k0 : k0 - 2048;
    const int srcB = (k0 < 1024) ? k0 : k0 - 1024;
    __syncthreads();
    #pragma unroll
    for (int i = 0; i < 4; ++i) {
      const int row = i * 32 + srow;
      const int u = su ^ (row & 7);
      gld16(A + (long long)(bm0 + row) * 2048 + srcA + u * 8,
            smem + i * 4096 + wv * 1024);
      gld16(Wt + (long long)row * 2048 + srcB + u * 8,
            smem + 16384 + i * 4096 + wv * 1024);
    }
    asm volatile("s_waitcnt vmcnt(0)" ::: "memory");
    __syncthreads();
    #pragma unroll
    for (int h = 0; h < 2; ++h) {
      bf16x8 af[4], bfr[4];
      #pragma unroll
      for (int i = 0; i < 4; ++i) {
        const int row = rAc + i * 16 + lrow;
        const int u = (h * 4 + lk) ^ (row & 7);
        af[i] = *(const bf16x8*)(smem + row * 128 + u * 16);
      }
      #pragma unroll
      for (int j = 0; j < 4; ++j) {
        const int row = rBc + j * 16 + lrow;
        const int u = (h * 4 + lk) ^ (row & 7);
        bfr[j] = *(const bf16x8*)(smem + 16384 + row * 128 + u * 16);
      }
      #pragma unroll
      for (int i = 0; i < 4; ++i)
        #pragma unroll
        for (int j = 0; j < 4; ++j)
          acc[i][j] = __builtin_amdgcn_mfma_f32_16x16x32_bf16(
              af[i], bfr[j], acc[i][j], 0, 0, 0);
    }
  }
  const int rg = lk * 4;
  #pragma unroll
  for (int j = 0; j < 4; ++j) {
    const int col = bn0 + rBc + j * 16 + lrow;
    const int cz = col & 1023;
    const float bj = bp[cz];
    const int hh = cz >> 6, e = cz & 63;
    #pragma unroll
    for (int i = 0; i < 4; ++i) {
      const int rbase = bm0 + rAc + i * 16 + rg;
      const int b = rbase >> 11;
      if (z < 2) {
        const int sbase = rbase & 2047;
        ushort* dst = pairout + (long long)z * 8388608 +
                      ((long long)(b * 16 + hh) * 2048 + sbase) * 128 + e;
        #pragma unroll
        for (int r = 0; r < 4; ++r) {
          float val = acc[i][j][r] + bj;
          ushort vh = f2bf(val);
          dst[r * 128] = vh;
          dst[r * 128 + 64] = f2bf(val - bf2f(vh));
        }
      } else {
        const int tb = rbase & 2047;
        ushort4 hi4, lo4;
        ushort* hp = (ushort*)&hi4; ushort* lp = (ushort*)&lo4;
        #pragma unroll
        for (int r = 0; r < 4; ++r) {
          float val = acc[i][j][r] + bj;
          ushort vh = f2bf(val);
          hp[r] = vh;
          lp[r] = f2bf(val - bf2f(vh));
        }
        ushort* vdst = pairout + 2ll * 8388608 +
                       (long long)(b * 16 + hh) * 262144 +
                       (long long)e * 2048 + tb;
        *(ushort4*)vdst = hi4;
        *(ushort4*)(vdst + 131072) = lo4;
      }
    }
  }
}

// =====================================================================
// Expert GEMM: plain bf16, K=1024, C f32 + bias. grid (8, 5, E).
// =====================================================================
__global__ __launch_bounds__(256) void expert_gemm(
    const ushort* __restrict__ A, const ushort* __restrict__ W,
    const float* __restrict__ be, float* __restrict__ C)
{
  __shared__ char smem[32768] __attribute__((aligned(128)));
  const int z = blockIdx.z;
  A += (long long)z * (ECAP * D);
  W += (long long)z * (D * D);
  C += (long long)z * (ECAP * D);
  const float* bp = be + (long long)z * D;
  const int tid = threadIdx.x;
  const int lane = tid & 63;
  const int lrow = lane & 15;
  const int lk = lane >> 4;
  const int wv = tid >> 6;
  const int rAc = (wv >> 1) * 64;
  const int rBc = (wv & 1) * 64;
  const int bm0 = blockIdx.y * 128;
  const int bn0 = blockIdx.x * 128;
  const int srow = tid >> 3;
  const int su = tid & 7;

  f32x4 acc[4][4] = {};
  for (int step = 0; step < 16; ++step) {
    const int k0 = step * 64;
    __syncthreads();
    #pragma unroll
    for (int i = 0; i < 4; ++i) {
      const int row = i * 32 + srow;
      const int u = su ^ (row & 7);
      gld16(A + (long long)(bm0 + row) * 1024 + k0 + u * 8,
            smem + i * 4096 + wv * 1024);
      gld16(W + (long long)(bn0 + row) * 1024 + k0 + u * 8,
            smem + 16384 + i * 4096 + wv * 1024);
    }
    asm volatile("s_waitcnt vmcnt(0)" ::: "memory");
    __syncthreads();
    #pragma unroll
    for (int h = 0; h < 2; ++h) {
      bf16x8 af[4], bfr[4];
      #pragma unroll
      for (int i = 0; i < 4; ++i) {
        const int row = rAc + i * 16 + lrow;
        const int u = (h * 4 + lk) ^ (row & 7);
        af[i] = *(const bf16x8*)(smem + row * 128 + u * 16);
      }
      #pragma unroll
      for (int j = 0; j < 4; ++j) {
        const int row = rBc + j * 16 + lrow;
        const int u = (h * 4 + lk) ^ (row & 7);
        bfr[j] = *(const bf16x8*)(smem + 16384 + row * 128 + u * 16);
      }
      #pragma unroll
      for (int i = 0; i < 4; ++i)
        #pragma unroll
        for (int j = 0; j < 4; ++j)
          acc[i][j] = __builtin_amdgcn_mfma_f32_16x16x32_bf16(
              af[i], bfr[j], acc[i][j], 0, 0, 0);
    }
  }
  const int rg = lk * 4;
  #pragma unroll
  for (int j = 0; j < 4; ++j) {
    const int col = bn0 + rBc + j * 16 + lrow;
    const float bj = bp[col];
    #pragma unroll
    for (int i = 0; i < 4; ++i) {
      const int rbase = bm0 + rAc + i * 16 + rg;
      #pragma unroll
      for (int r = 0; r < 4; ++r)
        C[(long long)(rbase + r) * 1024 + col] = acc[i][j][r] + bj;
    }
  }
}

// =====================================================================
// Suffix sums over t from vtp pairs: vsuf[bh*64+e][t] = sum_{t'>=t} v
// =====================================================================
__global__ __launch_bounds__(256) void suffix_kernel(const ushort* __restrict__ vtp,
                                                     float* __restrict__ vsuf)
{
  const int R = blockIdx.x;        // bh*64+e
  const int bh = R >> 6, e = R & 63;
  const ushort* hi = vtp + (long long)bh * 262144 + (long long)e * 2048;
  const ushort* lo = hi + 131072;
  const int tid = threadIdx.x;
  ushort4 h0 = *(const ushort4*)(hi + tid * 8);
  ushort4 h1 = *(const ushort4*)(hi + tid * 8 + 4);
  ushort4 l0 = *(const ushort4*)(lo + tid * 8);
  ushort4 l1 = *(const ushort4*)(lo + tid * 8 + 4);
  float v[8];
  v[0] = bf2f(h0.x) + bf2f(l0.x); v[1] = bf2f(h0.y) + bf2f(l0.y);
  v[2] = bf2f(h0.z) + bf2f(l0.z); v[3] = bf2f(h0.w) + bf2f(l0.w);
  v[4] = bf2f(h1.x) + bf2f(l1.x); v[5] = bf2f(h1.y) + bf2f(l1.y);
  v[6] = bf2f(h1.z) + bf2f(l1.z); v[7] = bf2f(h1.w) + bf2f(l1.w);
  float s = 0.f;
  #pragma unroll
  for (int x = 0; x < 8; ++x) s += v[x];
  __shared__ float ss[256];
  ss[tid] = s;
  __syncthreads();
  for (int off = 1; off < 256; off <<= 1) {
    float t = (tid + off < 256) ? ss[tid + off] : 0.f;
    __syncthreads();
    ss[tid] += t;
    __syncthreads();
  }
  float acc = (tid < 255) ? ss[tid + 1] : 0.f;
  float out[8];
  for (int x = 7; x >= 0; --x) { acc += v[x]; out[x] = acc; }
  #pragma unroll
  for (int x = 0; x < 8; ++x)
    vsuf[(long long)R * 2048 + tid * 8 + x] = out[x];
}

// =====================================================================
// MFMA attention v3: 128-row Q-tile, 8 waves, 64KB LDS (2 blocks/CU).
// Swapped QK^T (mfma(K,Q)) -> P lane-local per q-col; in-register
// P exchange (32 shfl) feeds PV A-frag; no wl LDS, 2 barriers/tile.
// Q lives in registers (staged once through the K-dbuf area).
//   out[s] = (sum_{t<=s} e^{qk/32} v_t + vsuf[s+1]) / (l + (S-1-s))
// =====================================================================
__device__ __forceinline__ void attn_stage_kv(
    const ushort* kbase, const ushort* vbase, int t0,
    char* kdst, char* vdst, int tid, int wv)
{
  #pragma unroll
  for (int i = 0; i < 2; ++i) {     // K: 64 rows x 16 units
    const int L = i * 512 + tid;
    const int row = L >> 4, u = L & 15;
    gld16(kbase + (long long)(t0 + row) * 128 + ((u ^ (row & 15)) * 8),
          kdst + i * 8192 + wv * 1024);
  }
  #pragma unroll
  for (int i = 0; i < 2; ++i) {     // V: 2 sec x 64 e-rows x 8 units
    const int L = i * 512 + tid;
    const int sec = L >> 9, vr = (L >> 3) & 63, u = L & 7;
    gld16(vbase + (long long)sec * 131072 + (long long)vr * 2048 + t0 +
              ((u ^ (vr & 7)) * 8),
          vdst + i * 8192 + wv * 1024);
  }
}

__global__ __launch_bounds__(512, 4) void attn_mfma(
    const ushort* __restrict__ qp, const ushort* __restrict__ kp,
    const ushort* __restrict__ vtp, const float* __restrict__ vsuf,
    float* __restrict__ hid)
{
  __shared__ char smem[65536] __attribute__((aligned(128)));
  // K slot s: smem + s*16384 (s=0,1); V slot s: smem + 32768 + s*16384
  const int tid = threadIdx.x;
  const int lane = tid & 63;
  const int wv = tid >> 6;            // 0..7
  const int g = lane >> 4, c = lane & 15;

  // work-id swizzle: XCD-chunked (4 bh per XCD) + balanced qi pairing
  const int flat = (int)(blockIdx.y * 16 + blockIdx.x);   // 0..511
  const int swz = (flat & 7) * 64 + (flat >> 3);
  const int bh = swz >> 4;
  const int bx = swz & 15;
  const int qi = ((bh >> 1) & 1) ? (15 - bx) : bx;
  const int sB0 = qi * 128;

  const ushort* qbase = qp + (long long)bh * (2048 * 128);
  const ushort* kbase = kp + (long long)bh * (2048 * 128);
  const ushort* vbase = vtp + (long long)bh * 262144;

  // ---- prologue: q through LDS (K-dbuf area) into registers ----
  #pragma unroll
  for (int i = 0; i < 4; ++i) {
    const int L = i * 512 + tid;
    const int row = L >> 4, u = L & 15;
    gld16(qbase + (long long)(sB0 + row) * 128 + ((u ^ (row & 15)) * 8),
          smem + i * 8192 + wv * 1024);
  }
  asm volatile("s_waitcnt vmcnt(0)" ::: "memory");
  __builtin_amdgcn_s_barrier();
  bf16x8 qh[2], ql[2];
  {
    const int qrow = wv * 16 + c;                 // qrow & 15 == c
    const ushort* qsl = (const ushort*)smem + qrow * 128;
    #pragma unroll
    for (int h = 0; h < 2; ++h) {
      qh[h] = *(const bf16x8*)(qsl + (((h * 4 + g) ^ c) * 8));
      ql[h] = *(const bf16x8*)(qsl + (((8 + h * 4 + g) ^ c) * 8));
    }
  }
  asm volatile("s_waitcnt lgkmcnt(0)" ::: "memory");
  __builtin_amdgcn_s_barrier();                   // q reads done; LDS reusable

  attn_stage_kv(kbase, vbase, 0, smem, smem + 32768, tid, wv);

  f32x4 oacc[4] = {};
  float l_acc = 0.f;
  const int nt = 2 * qi + 2;
  const int srcA = ((lane >> 4) & 1) * 32 + c;    // exchange source lanes
  const int srcB = srcA + 16;
  const bool ghi = lane >= 32;

  for (int t = 0; t < nt; ++t) {
    const int t0 = t * 64;
    char* kcur = smem + (t & 1) * 16384;
    char* vcur = smem + 32768 + (t & 1) * 16384;
    if (t + 1 < nt) {
      attn_stage_kv(kbase, vbase, t0 + 64,
                    smem + ((t + 1) & 1) * 16384,
                    smem + 32768 + ((t + 1) & 1) * 16384, tid, wv);
      asm volatile("s_waitcnt vmcnt(4)" ::: "memory");  // tile t landed
    } else {
      asm volatile("s_waitcnt vmcnt(0)" ::: "memory");
    }
    __builtin_amdgcn_s_barrier();   // all waves: tile t ready; prev reads done

    const ushort* ks = (const ushort*)kcur;
    const ushort* vt = (const ushort*)vcur;

    // ---- QK^T swapped (3-term): acc[j][r] = P[t=j*16+4g+r][q=c] ----
    f32x4 acc[4] = {};
    __builtin_amdgcn_s_setprio(1);
    #pragma unroll
    for (int h = 0; h < 2; ++h) {
      #pragma unroll
      for (int j = 0; j < 4; ++j) {
        const int krow = j * 16 + c;              // krow & 15 == c
        const ushort* kr = ks + krow * 128;
        bf16x8 kh = *(const bf16x8*)(kr + (((h * 4 + g) ^ c) * 8));
        bf16x8 kl = *(const bf16x8*)(kr + (((8 + h * 4 + g) ^ c) * 8));
        acc[j] = __builtin_amdgcn_mfma_f32_16x16x32_bf16(kh, qh[h], acc[j], 0, 0, 0);
        acc[j] = __builtin_amdgcn_mfma_f32_16x16x32_bf16(kl, qh[h], acc[j], 0, 0, 0);
        acc[j] = __builtin_amdgcn_mfma_f32_16x16x32_bf16(kh, ql[h], acc[j], 0, 0, 0);
      }
    }
    __builtin_amdgcn_s_setprio(0);

    // ---- mask + exp + pack(hi|lo) + denominator ----
    unsigned int pw[16];
    float prt = 0.f;
    const int sg_c = sB0 + wv * 16 + c;           // this lane's q row
    #pragma unroll
    for (int j = 0; j < 4; ++j)
      #pragma unroll
      for (int r = 0; r < 4; ++r) {
        const int tg = t0 + j * 16 + 4 * g + r;
        float w = (tg <= sg_c) ? __expf(acc[j][r] * INV_SQRT_D) : 0.f;
        prt += w;
        ushort hi = f2bf(w);
        ushort lo = f2bf(w - bf2f(hi));
        pw[j * 4 + r] = (unsigned)hi | ((unsigned)lo << 16);
      }
    prt += __shfl_xor(prt, 16);
    prt += __shfl_xor(prt, 32);
    l_acc += prt;

    // ---- in-register P exchange -> PV A-fragments ----
    unsigned int paw[2][8];
    #pragma unroll
    for (int h = 0; h < 2; ++h)
      #pragma unroll
      for (int r = 0; r < 4; ++r) {
        unsigned a0 = (unsigned)__shfl((int)pw[(2 * h) * 4 + r], srcA);
        unsigned a1 = (unsigned)__shfl((int)pw[(2 * h + 1) * 4 + r], srcA);
        unsigned b0 = (unsigned)__shfl((int)pw[(2 * h) * 4 + r], srcB);
        unsigned b1 = (unsigned)__shfl((int)pw[(2 * h + 1) * 4 + r], srcB);
        paw[h][r] = ghi ? a1 : a0;
        paw[h][4 + r] = ghi ? b1 : b0;
      }
    bf16x8 pah[2], pal[2];
    #pragma unroll
    for (int h = 0; h < 2; ++h) {
      u32x4 hv, lv;
      #pragma unroll
      for (int p = 0; p < 4; ++p) {
        hv[p] = (paw[h][2 * p] & 0xffffu) | (paw[h][2 * p + 1] << 16);
        lv[p] = (paw[h][2 * p] >> 16) | (paw[h][2 * p + 1] & 0xffff0000u);
      }
      pah[h] = __builtin_bit_cast(bf16x8, hv);
      pal[h] = __builtin_bit_cast(bf16x8, lv);
    }

    // ---- PV (3-term): oacc[j][r] = out[q=4g+r][e=j*16+c] ----
    __builtin_amdgcn_s_setprio(1);
    #pragma unroll
    for (int h = 0; h < 2; ++h)
      #pragma unroll
      for (int j = 0; j < 4; ++j) {
        const int vrow = j * 16 + c;              // vrow & 7 == c & 7
        const ushort* vr = vt + vrow * 64;
        bf16x8 vh = *(const bf16x8*)(vr + (((h * 4 + g) ^ (c & 7)) * 8));
        bf16x8 vl = *(const bf16x8*)(vr + 4096 + (((h * 4 + g) ^ (c & 7)) * 8));
        oacc[j] = __builtin_amdgcn_mfma_f32_16x16x32_bf16(pah[h], vh, oacc[j], 0, 0, 0);
        oacc[j] = __builtin_amdgcn_mfma_f32_16x16x32_bf16(pal[h], vh, oacc[j], 0, 0, 0);
        oacc[j] = __builtin_amdgcn_mfma_f32_16x16x32_bf16(pah[h], vl, oacc[j], 0, 0, 0);
      }
    __builtin_amdgcn_s_setprio(0);
    asm volatile("s_waitcnt lgkmcnt(0)" ::: "memory");
    __builtin_amdgcn_s_barrier();   // all reads of tile t done -> safe overwrite
  }

  // ---- epilogue ----
  const int b = bh >> 4, hh = bh & 15;
  #pragma unroll
  for (int r = 0; r < 4; ++r) {
    const float lr = __shfl(l_acc, (lane & 48) | (4 * g + r));  // l for q=4g+r
    const int sg = sB0 + wv * 16 + 4 * g + r;
    const float denom = lr + (float)(S - 1 - sg);
    #pragma unroll
    for (int j = 0; j < 4; ++j) {
      const int e = j * 16 + c;
      const float suf = (sg + 1 < S) ? vsuf[((long long)bh * 64 + e) * 2048 + sg + 1] : 0.f;
      hid[(long long)(b * S + sg) * 1024 + hh * 64 + e] = (oacc[j][r] + suf) / denom;
    }
  }
}

// =====================================================================
// Router: 4 tokens per block (one per wave), vectorized.
// =====================================================================
__global__ __launch_bounds__(256) void router_kernel(
    const float* __restrict__ x, const float* __restrict__ Wsw,
    const float* __restrict__ bsw, int* __restrict__ routes,
    float* __restrict__ rprob)
{
  const int w = threadIdx.x >> 6, lane = threadIdx.x & 63;
  const int i = blockIdx.x * 4 + w;
  float p[E] = {};
  const float4* xr = (const float4*)(x + (long long)i * D);
  #pragma unroll
  for (int t = 0; t < 4; ++t) {
    float4 xv = xr[lane + 64 * t];
    #pragma unroll
    for (int e = 0; e < E; ++e) {
      float4 wv = ((const float4*)(Wsw + e * D))[lane + 64 * t];
      p[e] += xv.x * wv.x + xv.y * wv.y + xv.z * wv.z + xv.w * wv.w;
    }
  }
  #pragma unroll
  for (int off = 32; off; off >>= 1)
    #pragma unroll
    for (int e = 0; e < E; ++e) p[e] += __shfl_xor(p[e], off);
  if (lane == 0) {
    float m = -1e30f; int arg = 0;
    #pragma unroll
    for (int e = 0; e < E; ++e) {
      float l = p[e] + bsw[e];
      if (l > m) { m = l; arg = e; }
      p[e] = l;
    }
    float sum = 0.f;
    #pragma unroll
    for (int e = 0; e < E; ++e) sum += __expf(p[e] - m);
    routes[i] = arg;
    rprob[i] = 1.f / sum;
  }
}

// =====================================================================
// Sequential-order capacity scan. slot = route*ECAP + pos (kept) else -1.
// =====================================================================
__global__ __launch_bounds__(256) void scan_kernel(const int* __restrict__ routes,
                                                   int* __restrict__ slot)
{
  __shared__ int hist[256][E];
  const int tid = threadIdx.x;
  const int per = N / 256;
  int cnt[E] = {};
  for (int j = 0; j < per; ++j) cnt[routes[tid * per + j]]++;
  #pragma unroll
  for (int e = 0; e < E; ++e) hist[tid][e] = cnt[e];
  __syncthreads();
  if (tid < E) {
    int run = 0;
    for (int t = 0; t < 256; ++t) { int tmp = hist[t][tid]; hist[t][tid] = run; run += tmp; }
  }
  __syncthreads();
  int run[E];
  #pragma unroll
  for (int e = 0; e < E; ++e) run[e] = hist[tid][e];
  for (int j = 0; j < per; ++j) {
    int i = tid * per + j;
    int r = routes[i];
    int pos = run[r]++;
    slot[i] = (pos < CAP) ? r * ECAP + pos : -1;
  }
}

// =====================================================================
// Dispatch: scatter kept tokens (fp32 -> bf16) into expert_in[slot]
// =====================================================================
__global__ __launch_bounds__(256) void dispatch_kernel(
    const float* __restrict__ x, const int* __restrict__ slot,
    ushort* __restrict__ expert_in)
{
  const int i = blockIdx.x;
  const int sl = slot[i];
  if (sl < 0) return;
  float4 xv = ((const float4*)&x[(long long)i * D])[threadIdx.x];
  ushort4 o;
  o.x = f2bf(xv.x); o.y = f2bf(xv.y); o.z = f2bf(xv.z); o.w = f2bf(xv.w);
  ((ushort4*)&expert_in[(long long)sl * D])[threadIdx.x] = o;
}

// =====================================================================
// Finalize: gather/passthrough, *route_prob, +embed, LayerNorm.
// =====================================================================
__global__ __launch_bounds__(256) void finalize_kernel(
    const float* __restrict__ x, const float* __restrict__ eout,
    const int* __restrict__ slot, const float* __restrict__ rprob,
    const float* __restrict__ embed, const float* __restrict__ gamma,
    const float* __restrict__ beta, float* __restrict__ out)
{
  const int i = blockIdx.x;
  const int tid = threadIdx.x;
  const int sl = slot[i];
  const float rp = rprob[i];
  const float4* src = (sl >= 0) ? (const float4*)&eout[(long long)sl * D]
                                : (const float4*)&x[(long long)i * D];
  float4 yv = src[tid];
  float4 ev = ((const float4*)&embed[(long long)i * D])[tid];
  float v0 = yv.x * rp + ev.x;
  float v1 = yv.y * rp + ev.y;
  float v2 = yv.z * rp + ev.z;
  float v3 = yv.w * rp + ev.w;
  float s1 = v0 + v1 + v2 + v3;
  float s2 = v0*v0 + v1*v1 + v2*v2 + v3*v3;
  #pragma unroll
  for (int off = 32; off; off >>= 1) {
    s1 += __shfl_xor(s1, off);
    s2 += __shfl_xor(s2, off);
  }
  __shared__ float wsum[4], wsq[4];
  const int wid = tid >> 6, lid = tid & 63;
  if (lid == 0) { wsum[wid] = s1; wsq[wid] = s2; }
  __syncthreads();
  float tot  = wsum[0] + wsum[1] + wsum[2] + wsum[3];
  float tot2 = wsq[0] + wsq[1] + wsq[2] + wsq[3];
  const float mean = tot * (1.f / D);
  const float var = tot2 * (1.f / D) - mean * mean;
  const float rstd = rsqrtf(var + 1e-5f);
  float4 gv = ((const float4*)gamma)[tid];
  float4 bv = ((const float4*)beta)[tid];
  float4 ov;
  ov.x = (v0 - mean) * rstd * gv.x + bv.x;
  ov.y = (v1 - mean) * rstd * gv.y + bv.y;
  ov.z = (v2 - mean) * rstd * gv.z + bv.z;
  ov.w = (v3 - mean) * rstd * gv.w + bv.w;
  ((float4*)&out[(long long)i * D])[tid] = ov;
}

// =====================================================================
extern "C" void kernel_launch(void* const* d_in, const int* in_sizes, int n_in,
                              void* d_out, int out_size, void* d_ws, size_t ws_size,
                              hipStream_t stream) {
  const float* embed = (const float*)d_in[0];
  const float* Wq = (const float*)d_in[1];
  const float* bq = (const float*)d_in[2];
  const float* Wk = (const float*)d_in[3];
  const float* bk = (const float*)d_in[4];
  const float* Wv = (const float*)d_in[5];
  const float* bv = (const float*)d_in[6];
  const float* We = (const float*)d_in[7];
  const float* be = (const float*)d_in[8];
  const float* Wsw = (const float*)d_in[9];
  const float* bsw = (const float*)d_in[10];
  const float* gamma = (const float*)d_in[11];
  const float* beta = (const float*)d_in[12];
  float* out = (float*)d_out;

  // Workspace layout (byte offsets), lifetime-aliased. Peak ~96.6MB.
  char* base = (char*)d_ws;
  ushort* epair      = (ushort*)base;                    // 16.8MB (GEMM in)
  float*  hid        = (float*)base;                     //   reuse after GEMM
  ushort* wpair      = (ushort*)(base + 16777216);       // 12.6MB (GEMM in)
  ushort* expert_in  = (ushort*)(base + 16777216);       //   reuse (10.5MB)
  ushort* pairs      = (ushort*)(base + 29360128);       // qp|kp|vtp 50.3MB
  float*  expert_out = (float*)(base + 29360128);        //   reuse (21MB)
  ushort* qp  = pairs;
  ushort* kp  = pairs + 8388608;
  ushort* vtp = pairs + 2 * 8388608;
  float*  vsuf = (float*)(base + 79691776);              // 16.8MB
  ushort* webf = (ushort*)(base + 79691776);             //   reuse after attn
  int*    routes = (int*)(base + 96468992);
  int*    slot   = routes + N;
  float*  rprob  = (float*)(slot + N);

  // 1. conversions: embed & Wq/Wk/Wv -> hi/lo pair arrays
  cvt_pair<<<N * D / 1024, 256, 0, stream>>>(embed, epair);
  cvt_pair<<<D * D / 1024, 256, 0, stream>>>(Wq, wpair + 0ll * D * 2048);
  cvt_pair<<<D * D / 1024, 256, 0, stream>>>(Wk, wpair + 1ll * D * 2048);
  cvt_pair<<<D * D / 1024, 256, 0, stream>>>(Wv, wpair + 2ll * D * 2048);
  // 2. merged QKV projection (split-bf16, N=3072) -> attention-layout pairs
  qkv_gemm<<<dim3(24, 32), 256, 0, stream>>>(epair, wpair, bq, bk, bv, pairs);
  // 3. suffix sums of v (from vtp pairs)
  suffix_kernel<<<B * H * 64, 256, 0, stream>>>(vtp, vsuf);
  // 4. MFMA attention v3 -> hiddens (64KB LDS, 2 blocks/CU)
  attn_mfma<<<dim3(16, 32), 512, 0, stream>>>(qp, kp, vtp, vsuf, hid);
  // 5. router
  router_kernel<<<N / 4, 256, 0, stream>>>(hid, Wsw, bsw, routes, rprob);
  // 6. capacity scan
  scan_kernel<<<1, 256, 0, stream>>>(routes, slot);
  // 7. We -> bf16 (overwrites vsuf; after attention)
  cvt_plain<<<(int)((long long)E * D * D / 1024), 256, 0, stream>>>(We, webf);
  // 8. dispatch tokens -> expert_in (bf16)
  dispatch_kernel<<<N, 256, 0, stream>>>(hid, slot, expert_in);
  // 9. expert GEMMs: plain bf16 (K=1024), M padded to 640
  expert_gemm<<<dim3(8, ECAP / 128, E), 256, 0, stream>>>(
      expert_in, webf, be, expert_out);
  // 10. gather + combine + residual + LayerNorm
  finalize_kernel<<<N, 256, 0, stream>>>(hid, expert_out, slot, rprob,
                                         embed, gamma, beta, out);
}

// Round 9
// 387.841 us; speedup vs baseline: 4.3050x; 1.0434x over previous
//
#include <hip/hip_runtime.h>

// Problem constants (match reference)
constexpr int B = 2, S = 2048, D = 1024, H = 16, E = 8, DH = 64;
constexpr int N = B * S;          // 4096 tokens
constexpr int CAP = 614;          // int(1.2 * N / E) -- capacity check
constexpr int ECAP = 640;         // padded rows per expert (5 * 128 tiles)
constexpr float INV_SQRT_D = 0.03125f;   // 1/sqrt(1024)

typedef __bf16 bf16x8 __attribute__((ext_vector_type(8)));
typedef float f32x4 __attribute__((ext_vector_type(4)));
typedef unsigned int u32x4 __attribute__((ext_vector_type(4)));

__device__ __forceinline__ ushort f2bf(float x) {
  __bf16 h = (__bf16)x;
  return __builtin_bit_cast(unsigned short, h);
}
__device__ __forceinline__ float bf2f(ushort u) {
  __bf16 h = __builtin_bit_cast(__bf16, u);
  return (float)h;
}
// 16B direct global->LDS. LDS dest is wave-uniform base (+ lane*16 by HW).
__device__ __forceinline__ void gld16(const void* g, void* l) {
  __builtin_amdgcn_global_load_lds(
      (const __attribute__((address_space(1))) unsigned int*)g,
      (__attribute__((address_space(3))) unsigned int*)l, 16, 0, 0);
}

// =====================================================================
// Merged fp32 -> bf16 hi/lo pair conversion for embed + Wq + Wk + Wv.
// Rows 0..4095 -> epair[row][2048]; rows 4096..7167 -> wpair[r2][2048].
// =====================================================================
__global__ __launch_bounds__(256) void cvt_all(
    const float* __restrict__ embed, const float* __restrict__ Wq,
    const float* __restrict__ Wk, const float* __restrict__ Wv,
    ushort* __restrict__ epair, ushort* __restrict__ wpair)
{
  const long long idx4 = (long long)blockIdx.x * 256 + threadIdx.x;
  const int row = (int)(idx4 >> 8);           // 256 float4 per 1024-row
  const int col = (int)((idx4 & 255) << 2);
  const float* src;
  ushort* dst;
  if (row < 4096) {
    src = embed + (long long)row * 1024;
    dst = epair + (long long)row * 2048;
  } else {
    const int r2 = row - 4096;
    const int z = r2 >> 10;
    const float* w = (z == 0) ? Wq : (z == 1) ? Wk : Wv;
    src = w + (long long)(r2 & 1023) * 1024;
    dst = wpair + (long long)r2 * 2048;
  }
  const float4 xv = *(const float4*)(src + col);
  float xs[4] = {xv.x, xv.y, xv.z, xv.w};
  ushort4 hi, lo;
  ushort* hp = (ushort*)&hi; ushort* lp = (ushort*)&lo;
  #pragma unroll
  for (int c = 0; c < 4; ++c) {
    ushort h = f2bf(xs[c]);
    hp[c] = h;
    lp[c] = f2bf(xs[c] - bf2f(h));
  }
  *(ushort4*)&dst[col] = hi;
  *(ushort4*)&dst[1024 + col] = lo;
}

// plain fp32 -> bf16, flat (for We)
__global__ __launch_bounds__(256) void cvt_plain(const float* __restrict__ in,
                                                 ushort* __restrict__ out)
{
  const long long idx4 = (long long)blockIdx.x * 256 + threadIdx.x;
  const float4 xv = ((const float4*)in)[idx4];
  ushort4 o;
  o.x = f2bf(xv.x); o.y = f2bf(xv.y); o.z = f2bf(xv.z); o.w = f2bf(xv.w);
  *(ushort4*)&out[idx4 * 4] = o;
}

// =====================================================================
// QKV GEMM merged over N=3072 (q|k|v). Split-bf16 hi/lo, logical K'=3072
// over pair arrays (hi*hi + lo*hi + hi*lo). 128x128 tile, BK=64, 4 waves.
// Epilogue writes attention-layout bf16 pairs:
//   z=0/1 (q/k): pairout[z][bh][s][128] (cols 0-63 hi, 64-127 lo)
//   z=2   (v)  : vtp[bh][sec][e][2048]  (transposed, sec=hi/lo)
// XCD swizzle: each XCD owns 3 n-panels x all 32 m-panels -> W working
// set 1.57MB (L2-resident per XCD), A panels get 3x temporal reuse.
// =====================================================================
__global__ __launch_bounds__(256) void qkv_gemm(
    const ushort* __restrict__ A, const ushort* __restrict__ Wp,
    const float* __restrict__ bq, const float* __restrict__ bk,
    const float* __restrict__ bv, ushort* __restrict__ pairout)
{
  __shared__ char smem[32768] __attribute__((aligned(128)));
  const int tid = threadIdx.x;
  const int lane = tid & 63;
  const int lrow = lane & 15;
  const int lk = lane >> 4;
  const int wv = tid >> 6;
  const int rAc = (wv >> 1) * 64;
  const int rBc = (wv & 1) * 64;
  const int flat = (int)(blockIdx.y * 24 + blockIdx.x);   // 0..767
  const int xcd = flat & 7;
  const int sub = flat >> 3;                              // 0..95
  const int bn0 = (xcd * 3 + sub % 3) * 128;              // 3 n-panels/XCD
  const int bm0 = (sub / 3) * 128;                        // m-major within XCD
  const int z = bn0 >> 10;                                // 0=q 1=k 2=v (uniform)
  const ushort* Wt = Wp + (long long)z * (1024 * 2048) +
                     (long long)(bn0 & 1023) * 2048;
  const float* bp = (z == 0) ? bq : (z == 1) ? bk : bv;
  const int srow = tid >> 3;
  const int su = tid & 7;

  f32x4 acc[4][4] = {};

  for (int step = 0; step < 48; ++step) {
    const int k0 = step * 64;
    const int srcA = (k0 < 2048) ? k0 : k0 - 2048;
    const int srcB = (k0 < 1024) ? k0 : k0 - 1024;
    __syncthreads();
    #pragma unroll
    for (int i = 0; i < 4; ++i) {
      const int row = i * 32 + srow;
      const int u = su ^ (row & 7);
      gld16(A + (long long)(bm0 + row) * 2048 + srcA + u * 8,
            smem + i * 4096 + wv * 1024);
      gld16(Wt + (long long)row * 2048 + srcB + u * 8,
            smem + 16384 + i * 4096 + wv * 1024);
    }
    asm volatile("s_waitcnt vmcnt(0)" ::: "memory");
    __syncthreads();
    #pragma unroll
    for (int h = 0; h < 2; ++h) {
      bf16x8 af[4], bfr[4];
      #pragma unroll
      for (int i = 0; i < 4; ++i) {
        const int row = rAc + i * 16 + lrow;
        const int u = (h * 4 + lk) ^ (row & 7);
        af[i] = *(const bf16x8*)(smem + row * 128 + u * 16);
      }
      #pragma unroll
      for (int j = 0; j < 4; ++j) {
        const int row = rBc + j * 16 + lrow;
        const int u = (h * 4 + lk) ^ (row & 7);
        bfr[j] = *(const bf16x8*)(smem + 16384 + row * 128 + u * 16);
      }
      #pragma unroll
      for (int i = 0; i < 4; ++i)
        #pragma unroll
        for (int j = 0; j < 4; ++j)
          acc[i][j] = __builtin_amdgcn_mfma_f32_16x16x32_bf16(
              af[i], bfr[j], acc[i][j], 0, 0, 0);
    }
  }
  const int rg = lk * 4;
  #pragma unroll
  for (int j = 0; j < 4; ++j) {
    const int col = bn0 + rBc + j * 16 + lrow;
    const int cz = col & 1023;
    const float bj = bp[cz];
    const int hh = cz >> 6, e = cz & 63;
    #pragma unroll
    for (int i = 0; i < 4; ++i) {
      const int rbase = bm0 + rAc + i * 16 + rg;
      const int b = rbase >> 11;
      if (z < 2) {
        const int sbase = rbase & 2047;
        ushort* dst = pairout + (long long)z * 8388608 +
                      ((long long)(b * 16 + hh) * 2048 + sbase) * 128 + e;
        #pragma unroll
        for (int r = 0; r < 4; ++r) {
          float val = acc[i][j][r] + bj;
          ushort vh = f2bf(val);
          dst[r * 128] = vh;
          dst[r * 128 + 64] = f2bf(val - bf2f(vh));
        }
      } else {
        const int tb = rbase & 2047;
        ushort4 hi4, lo4;
        ushort* hp = (ushort*)&hi4; ushort* lp = (ushort*)&lo4;
        #pragma unroll
        for (int r = 0; r < 4; ++r) {
          float val = acc[i][j][r] + bj;
          ushort vh = f2bf(val);
          hp[r] = vh;
          lp[r] = f2bf(val - bf2f(vh));
        }
        ushort* vdst = pairout + 2ll * 8388608 +
                       (long long)(b * 16 + hh) * 262144 +
                       (long long)e * 2048 + tb;
        *(ushort4*)vdst = hi4;
        *(ushort4*)(vdst + 131072) = lo4;
      }
    }
  }
}

// =====================================================================
// Expert GEMM: plain bf16, K=1024, C f32 + bias. grid (8, 5, E).
// =====================================================================
__global__ __launch_bounds__(256) void expert_gemm(
    const ushort* __restrict__ A, const ushort* __restrict__ W,
    const float* __restrict__ be, float* __restrict__ C)
{
  __shared__ char smem[32768] __attribute__((aligned(128)));
  const int z = blockIdx.z;
  A += (long long)z * (ECAP * D);
  W += (long long)z * (D * D);
  C += (long long)z * (ECAP * D);
  const float* bp = be + (long long)z * D;
  const int tid = threadIdx.x;
  const int lane = tid & 63;
  const int lrow = lane & 15;
  const int lk = lane >> 4;
  const int wv = tid >> 6;
  const int rAc = (wv >> 1) * 64;
  const int rBc = (wv & 1) * 64;
  const int bm0 = blockIdx.y * 128;
  const int bn0 = blockIdx.x * 128;
  const int srow = tid >> 3;
  const int su = tid & 7;

  f32x4 acc[4][4] = {};
  for (int step = 0; step < 16; ++step) {
    const int k0 = step * 64;
    __syncthreads();
    #pragma unroll
    for (int i = 0; i < 4; ++i) {
      const int row = i * 32 + srow;
      const int u = su ^ (row & 7);
      gld16(A + (long long)(bm0 + row) * 1024 + k0 + u * 8,
            smem + i * 4096 + wv * 1024);
      gld16(W + (long long)(bn0 + row) * 1024 + k0 + u * 8,
            smem + 16384 + i * 4096 + wv * 1024);
    }
    asm volatile("s_waitcnt vmcnt(0)" ::: "memory");
    __syncthreads();
    #pragma unroll
    for (int h = 0; h < 2; ++h) {
      bf16x8 af[4], bfr[4];
      #pragma unroll
      for (int i = 0; i < 4; ++i) {
        const int row = rAc + i * 16 + lrow;
        const int u = (h * 4 + lk) ^ (row & 7);
        af[i] = *(const bf16x8*)(smem + row * 128 + u * 16);
      }
      #pragma unroll
      for (int j = 0; j < 4; ++j) {
        const int row = rBc + j * 16 + lrow;
        const int u = (h * 4 + lk) ^ (row & 7);
        bfr[j] = *(const bf16x8*)(smem + 16384 + row * 128 + u * 16);
      }
      #pragma unroll
      for (int i = 0; i < 4; ++i)
        #pragma unroll
        for (int j = 0; j < 4; ++j)
          acc[i][j] = __builtin_amdgcn_mfma_f32_16x16x32_bf16(
              af[i], bfr[j], acc[i][j], 0, 0, 0);
    }
  }
  const int rg = lk * 4;
  #pragma unroll
  for (int j = 0; j < 4; ++j) {
    const int col = bn0 + rBc + j * 16 + lrow;
    const float bj = bp[col];
    #pragma unroll
    for (int i = 0; i < 4; ++i) {
      const int rbase = bm0 + rAc + i * 16 + rg;
      #pragma unroll
      for (int r = 0; r < 4; ++r)
        C[(long long)(rbase + r) * 1024 + col] = acc[i][j][r] + bj;
    }
  }
}

// =====================================================================
// Per-128-chunk column sums of v from vtp pairs:
//   csum[bh][c][e] = sum_{t in [c*128,(c+1)*128)} v[t][e]
// =====================================================================
__global__ __launch_bounds__(64) void vchunk_sum(const ushort* __restrict__ vtp,
                                                 float* __restrict__ csum)
{
  const int bh = blockIdx.x, c = blockIdx.y, e = threadIdx.x;
  const ushort* base = vtp + (long long)bh * 262144 + (long long)e * 2048 + c * 128;
  float s = 0.f;
  #pragma unroll
  for (int sec = 0; sec < 2; ++sec) {
    const ushort* p = base + sec * 131072;
    for (int i = 0; i < 16; ++i) {
      ushort4 a = *(const ushort4*)(p + i * 8);
      ushort4 b = *(const ushort4*)(p + i * 8 + 4);
      s += bf2f(a.x) + bf2f(a.y) + bf2f(a.z) + bf2f(a.w);
      s += bf2f(b.x) + bf2f(b.y) + bf2f(b.z) + bf2f(b.w);
    }
  }
  csum[((long long)bh * 16 + c) * 64 + e] = s;
}

// suffix over chunks: vsufC[bh][k][e] = sum_{c >= k} csum[bh][c][e], k<=16
__global__ __launch_bounds__(64) void vchunk_suffix(const float* __restrict__ csum,
                                                    float* __restrict__ vsufC)
{
  const int bh = blockIdx.x, e = threadIdx.x;
  float acc = 0.f;
  vsufC[((long long)bh * 17 + 16) * 64 + e] = 0.f;
  for (int c = 15; c >= 0; --c) {
    acc += csum[((long long)bh * 16 + c) * 64 + e];
    vsufC[((long long)bh * 17 + c) * 64 + e] = acc;
  }
}

// =====================================================================
// MFMA attention v3b: 128-row Q-tile, 8 waves, 64KB LDS (2 blocks/CU).
// Swapped QK^T (mfma(K,Q)) -> P lane-local; in-register P exchange.
// Masked-zero softmax handled IN-RANGE via w=1 for t>s (exp(0)=1), only
// the beyond-tile tail comes from the chunk-suffix table vsufC:
//   out[s] = (sum_{t<(qi+1)*128} w_t v_t + vsufC[qi+1]) / (l + tailcnt)
// =====================================================================
__device__ __forceinline__ void attn_stage_kv(
    const ushort* kbase, const ushort* vbase, int t0,
    char* kdst, char* vdst, int tid, int wv)
{
  #pragma unroll
  for (int i = 0; i < 2; ++i) {     // K: 64 rows x 16 units
    const int L = i * 512 + tid;
    const int row = L >> 4, u = L & 15;
    gld16(kbase + (long long)(t0 + row) * 128 + ((u ^ (row & 15)) * 8),
          kdst + i * 8192 + wv * 1024);
  }
  #pragma unroll
  for (int i = 0; i < 2; ++i) {     // V: 2 sec x 64 e-rows x 8 units
    const int L = i * 512 + tid;
    const int sec = L >> 9, vr = (L >> 3) & 63, u = L & 7;
    gld16(vbase + (long long)sec * 131072 + (long long)vr * 2048 + t0 +
              ((u ^ (vr & 7)) * 8),
          vdst + i * 8192 + wv * 1024);
  }
}

__global__ __launch_bounds__(512, 4) void attn_mfma(
    const ushort* __restrict__ qp, const ushort* __restrict__ kp,
    const ushort* __restrict__ vtp, const float* __restrict__ vsufC,
    float* __restrict__ hid)
{
  __shared__ char smem[65536] __attribute__((aligned(128)));
  const int tid = threadIdx.x;
  const int lane = tid & 63;
  const int wv = tid >> 6;            // 0..7
  const int g = lane >> 4, c = lane & 15;

  // work-id swizzle: XCD-chunked (4 bh per XCD) + balanced qi pairing
  const int flat = (int)(blockIdx.y * 16 + blockIdx.x);   // 0..511
  const int swz = (flat & 7) * 64 + (flat >> 3);
  const int bh = swz >> 4;
  const int bx = swz & 15;
  const int qi = ((bh >> 1) & 1) ? (15 - bx) : bx;
  const int sB0 = qi * 128;

  const ushort* qbase = qp + (long long)bh * (2048 * 128);
  const ushort* kbase = kp + (long long)bh * (2048 * 128);
  const ushort* vbase = vtp + (long long)bh * 262144;

  // ---- prologue: q through LDS (K-dbuf area) into registers ----
  #pragma unroll
  for (int i = 0; i < 4; ++i) {
    const int L = i * 512 + tid;
    const int row = L >> 4, u = L & 15;
    gld16(qbase + (long long)(sB0 + row) * 128 + ((u ^ (row & 15)) * 8),
          smem + i * 8192 + wv * 1024);
  }
  asm volatile("s_waitcnt vmcnt(0)" ::: "memory");
  __builtin_amdgcn_s_barrier();
  bf16x8 qh[2], ql[2];
  {
    const int qrow = wv * 16 + c;                 // qrow & 15 == c
    const ushort* qsl = (const ushort*)smem + qrow * 128;
    #pragma unroll
    for (int h = 0; h < 2; ++h) {
      qh[h] = *(const bf16x8*)(qsl + (((h * 4 + g) ^ c) * 8));
      ql[h] = *(const bf16x8*)(qsl + (((8 + h * 4 + g) ^ c) * 8));
    }
  }
  asm volatile("s_waitcnt lgkmcnt(0)" ::: "memory");
  __builtin_amdgcn_s_barrier();                   // q reads done; LDS reusable

  attn_stage_kv(kbase, vbase, 0, smem, smem + 32768, tid, wv);

  f32x4 oacc[4] = {};
  float l_acc = 0.f;
  const int nt = 2 * qi + 2;
  const int srcA = ((lane >> 4) & 1) * 32 + c;    // exchange source lanes
  const int srcB = srcA + 16;
  const bool ghi = lane >= 32;

  for (int t = 0; t < nt; ++t) {
    const int t0 = t * 64;
    char* kcur = smem + (t & 1) * 16384;
    char* vcur = smem + 32768 + (t & 1) * 16384;
    if (t + 1 < nt) {
      attn_stage_kv(kbase, vbase, t0 + 64,
                    smem + ((t + 1) & 1) * 16384,
                    smem + 32768 + ((t + 1) & 1) * 16384, tid, wv);
      asm volatile("s_waitcnt vmcnt(4)" ::: "memory");  // tile t landed
    } else {
      asm volatile("s_waitcnt vmcnt(0)" ::: "memory");
    }
    __builtin_amdgcn_s_barrier();   // all waves: tile t ready; prev reads done

    const ushort* ks = (const ushort*)kcur;
    const ushort* vt = (const ushort*)vcur;

    // ---- QK^T swapped (3-term): acc[j][r] = P[t=j*16+4g+r][q=c] ----
    f32x4 acc[4] = {};
    __builtin_amdgcn_s_setprio(1);
    #pragma unroll
    for (int h = 0; h < 2; ++h) {
      #pragma unroll
      for (int j = 0; j < 4; ++j) {
        const int krow = j * 16 + c;              // krow & 15 == c
        const ushort* kr = ks + krow * 128;
        bf16x8 kh = *(const bf16x8*)(kr + (((h * 4 + g) ^ c) * 8));
        bf16x8 kl = *(const bf16x8*)(kr + (((8 + h * 4 + g) ^ c) * 8));
        acc[j] = __builtin_amdgcn_mfma_f32_16x16x32_bf16(kh, qh[h], acc[j], 0, 0, 0);
        acc[j] = __builtin_amdgcn_mfma_f32_16x16x32_bf16(kl, qh[h], acc[j], 0, 0, 0);
        acc[j] = __builtin_amdgcn_mfma_f32_16x16x32_bf16(kh, ql[h], acc[j], 0, 0, 0);
      }
    }
    __builtin_amdgcn_s_setprio(0);

    // ---- mask(w=1 for unmasked-as-zero) + exp + pack(hi|lo) + denom ----
    unsigned int pw[16];
    float prt = 0.f;
    const int sg_c = sB0 + wv * 16 + c;           // this lane's q row
    #pragma unroll
    for (int j = 0; j < 4; ++j)
      #pragma unroll
      for (int r = 0; r < 4; ++r) {
        const int tg = t0 + j * 16 + 4 * g + r;
        float w = (tg <= sg_c) ? __expf(acc[j][r] * INV_SQRT_D) : 1.0f;
        prt += w;
        ushort hi = f2bf(w);
        ushort lo = f2bf(w - bf2f(hi));
        pw[j * 4 + r] = (unsigned)hi | ((unsigned)lo << 16);
      }
    prt += __shfl_xor(prt, 16);
    prt += __shfl_xor(prt, 32);
    l_acc += prt;

    // ---- in-register P exchange -> PV A-fragments ----
    unsigned int paw[2][8];
    #pragma unroll
    for (int h = 0; h < 2; ++h)
      #pragma unroll
      for (int r = 0; r < 4; ++r) {
        unsigned a0 = (unsigned)__shfl((int)pw[(2 * h) * 4 + r], srcA);
        unsigned a1 = (unsigned)__shfl((int)pw[(2 * h + 1) * 4 + r], srcA);
        unsigned b0 = (unsigned)__shfl((int)pw[(2 * h) * 4 + r], srcB);
        unsigned b1 = (unsigned)__shfl((int)pw[(2 * h + 1) * 4 + r], srcB);
        paw[h][r] = ghi ? a1 : a0;
        paw[h][4 + r] = ghi ? b1 : b0;
      }
    bf16x8 pah[2], pal[2];
    #pragma unroll
    for (int h = 0; h < 2; ++h) {
      u32x4 hv, lv;
      #pragma unroll
      for (int p = 0; p < 4; ++p) {
        hv[p] = (paw[h][2 * p] & 0xffffu) | (paw[h][2 * p + 1] << 16);
        lv[p] = (paw[h][2 * p] >> 16) | (paw[h][2 * p + 1] & 0xffff0000u);
      }
      pah[h] = __builtin_bit_cast(bf16x8, hv);
      pal[h] = __builtin_bit_cast(bf16x8, lv);
    }

    // ---- PV (3-term): oacc[j][r] = out[q=4g+r][e=j*16+c] ----
    __builtin_amdgcn_s_setprio(1);
    #pragma unroll
    for (int h = 0; h < 2; ++h)
      #pragma unroll
      for (int j = 0; j < 4; ++j) {
        const int vrow = j * 16 + c;              // vrow & 7 == c & 7
        const ushort* vr = vt + vrow * 64;
        bf16x8 vh = *(const bf16x8*)(vr + (((h * 4 + g) ^ (c & 7)) * 8));
        bf16x8 vl = *(const bf16x8*)(vr + 4096 + (((h * 4 + g) ^ (c & 7)) * 8));
        oacc[j] = __builtin_amdgcn_mfma_f32_16x16x32_bf16(pah[h], vh, oacc[j], 0, 0, 0);
        oacc[j] = __builtin_amdgcn_mfma_f32_16x16x32_bf16(pal[h], vh, oacc[j], 0, 0, 0);
        oacc[j] = __builtin_amdgcn_mfma_f32_16x16x32_bf16(pah[h], vl, oacc[j], 0, 0, 0);
      }
    __builtin_amdgcn_s_setprio(0);
    asm volatile("s_waitcnt lgkmcnt(0)" ::: "memory");
    __builtin_amdgcn_s_barrier();   // all reads of tile t done -> safe overwrite
  }

  // ---- epilogue: tail suffix + normalize ----
  const int b = bh >> 4, hh = bh & 15;
  const float tailcnt = (float)(S - (qi + 1) * 128);
  const float* sufp = vsufC + ((long long)bh * 17 + (qi + 1)) * 64;
  #pragma unroll
  for (int r = 0; r < 4; ++r) {
    const float lr = __shfl(l_acc, (lane & 48) | (4 * g + r));  // l for q=4g+r
    const int sg = sB0 + wv * 16 + 4 * g + r;
    const float denom = lr + tailcnt;
    #pragma unroll
    for (int j = 0; j < 4; ++j) {
      const int e = j * 16 + c;
      hid[(long long)(b * S + sg) * 1024 + hh * 64 + e] =
          (oacc[j][r] + sufp[e]) / denom;
    }
  }
}

// =====================================================================
// Router: 4 tokens per block (one per wave), vectorized.
// =====================================================================
__global__ __launch_bounds__(256) void router_kernel(
    const float* __restrict__ x, const float* __restrict__ Wsw,
    const float* __restrict__ bsw, int* __restrict__ routes,
    float* __restrict__ rprob)
{
  const int w = threadIdx.x >> 6, lane = threadIdx.x & 63;
  const int i = blockIdx.x * 4 + w;
  float p[E] = {};
  const float4* xr = (const float4*)(x + (long long)i * D);
  #pragma unroll
  for (int t = 0; t < 4; ++t) {
    float4 xv = xr[lane + 64 * t];
    #pragma unroll
    for (int e = 0; e < E; ++e) {
      float4 wv = ((const float4*)(Wsw + e * D))[lane + 64 * t];
      p[e] += xv.x * wv.x + xv.y * wv.y + xv.z * wv.z + xv.w * wv.w;
    }
  }
  #pragma unroll
  for (int off = 32; off; off >>= 1)
    #pragma unroll
    for (int e = 0; e < E; ++e) p[e] += __shfl_xor(p[e], off);
  if (lane == 0) {
    float m = -1e30f; int arg = 0;
    #pragma unroll
    for (int e = 0; e < E; ++e) {
      float l = p[e] + bsw[e];
      if (l > m) { m = l; arg = e; }
      p[e] = l;
    }
    float sum = 0.f;
    #pragma unroll
    for (int e = 0; e < E; ++e) sum += __expf(p[e] - m);
    routes[i] = arg;
    rprob[i] = 1.f / sum;
  }
}

// =====================================================================
// Sequential-order capacity scan. slot = route*ECAP + pos (kept) else -1.
// =====================================================================
__global__ __launch_bounds__(256) void scan_kernel(const int* __restrict__ routes,
                                                   int* __restrict__ slot)
{
  __shared__ int hist[256][E];
  const int tid = threadIdx.x;
  const int per = N / 256;
  int cnt[E] = {};
  for (int j = 0; j < per; ++j) cnt[routes[tid * per + j]]++;
  #pragma unroll
  for (int e = 0; e < E; ++e) hist[tid][e] = cnt[e];
  __syncthreads();
  if (tid < E) {
    int run = 0;
    for (int t = 0; t < 256; ++t) { int tmp = hist[t][tid]; hist[t][tid] = run; run += tmp; }
  }
  __syncthreads();
  int run[E];
  #pragma unroll
  for (int e = 0; e < E; ++e) run[e] = hist[tid][e];
  for (int j = 0; j < per; ++j) {
    int i = tid * per + j;
    int r = routes[i];
    int pos = run[r]++;
    slot[i] = (pos < CAP) ? r * ECAP + pos : -1;
  }
}

// =====================================================================
// Dispatch: scatter kept tokens (fp32 -> bf16) into expert_in[slot]
// =====================================================================
__global__ __launch_bounds__(256) void dispatch_kernel(
    const float* __restrict__ x, const int* __restrict__ slot,
    ushort* __restrict__ expert_in)
{
  const int i = blockIdx.x;
  const int sl = slot[i];
  if (sl < 0) return;
  float4 xv = ((const float4*)&x[(long long)i * D])[threadIdx.x];
  ushort4 o;
  o.x = f2bf(xv.x); o.y = f2bf(xv.y); o.z = f2bf(xv.z); o.w = f2bf(xv.w);
  ((ushort4*)&expert_in[(long long)sl * D])[threadIdx.x] = o;
}

// =====================================================================
// Finalize: gather/passthrough, *route_prob, +embed, LayerNorm.
// =====================================================================
__global__ __launch_bounds__(256) void finalize_kernel(
    const float* __restrict__ x, const float* __restrict__ eout,
    const int* __restrict__ slot, const float* __restrict__ rprob,
    const float* __restrict__ embed, const float* __restrict__ gamma,
    const float* __restrict__ beta, float* __restrict__ out)
{
  const int i = blockIdx.x;
  const int tid = threadIdx.x;
  const int sl = slot[i];
  const float rp = rprob[i];
  const float4* src = (sl >= 0) ? (const float4*)&eout[(long long)sl * D]
                                : (const float4*)&x[(long long)i * D];
  float4 yv = src[tid];
  float4 ev = ((const float4*)&embed[(long long)i * D])[tid];
  float v0 = yv.x * rp + ev.x;
  float v1 = yv.y * rp + ev.y;
  float v2 = yv.z * rp + ev.z;
  float v3 = yv.w * rp + ev.w;
  float s1 = v0 + v1 + v2 + v3;
  float s2 = v0*v0 + v1*v1 + v2*v2 + v3*v3;
  #pragma unroll
  for (int off = 32; off; off >>= 1) {
    s1 += __shfl_xor(s1, off);
    s2 += __shfl_xor(s2, off);
  }
  __shared__ float wsum[4], wsq[4];
  const int wid = tid >> 6, lid = tid & 63;
  if (lid == 0) { wsum[wid] = s1; wsq[wid] = s2; }
  __syncthreads();
  float tot  = wsum[0] + wsum[1] + wsum[2] + wsum[3];
  float tot2 = wsq[0] + wsq[1] + wsq[2] + wsq[3];
  const float mean = tot * (1.f / D);
  const float var = tot2 * (1.f / D) - mean * mean;
  const float rstd = rsqrtf(var + 1e-5f);
  float4 gv = ((const float4*)gamma)[tid];
  float4 bv = ((const float4*)beta)[tid];
  float4 ov;
  ov.x = (v0 - mean) * rstd * gv.x + bv.x;
  ov.y = (v1 - mean) * rstd * gv.y + bv.y;
  ov.z = (v2 - mean) * rstd * gv.z + bv.z;
  ov.w = (v3 - mean) * rstd * gv.w + bv.w;
  ((float4*)&out[(long long)i * D])[tid] = ov;
}

// =====================================================================
extern "C" void kernel_launch(void* const* d_in, const int* in_sizes, int n_in,
                              void* d_out, int out_size, void* d_ws, size_t ws_size,
                              hipStream_t stream) {
  const float* embed = (const float*)d_in[0];
  const float* Wq = (const float*)d_in[1];
  const float* bq = (const float*)d_in[2];
  const float* Wk = (const float*)d_in[3];
  const float* bk = (const float*)d_in[4];
  const float* Wv = (const float*)d_in[5];
  const float* bv = (const float*)d_in[6];
  const float* We = (const float*)d_in[7];
  const float* be = (const float*)d_in[8];
  const float* Wsw = (const float*)d_in[9];
  const float* bsw = (const float*)d_in[10];
  const float* gamma = (const float*)d_in[11];
  const float* beta = (const float*)d_in[12];
  float* out = (float*)d_out;

  // Workspace layout (byte offsets), lifetime-aliased. Peak ~97.3MB.
  char* base = (char*)d_ws;
  ushort* epair      = (ushort*)base;                    // 16.8MB (GEMM in)
  float*  hid        = (float*)base;                     //   reuse after GEMM
  ushort* wpair      = (ushort*)(base + 16777216);       // 12.6MB (GEMM in)
  ushort* expert_in  = (ushort*)(base + 16777216);       //   reuse (10.5MB)
  ushort* pairs      = (ushort*)(base + 29360128);       // qp|kp|vtp 50.3MB
  float*  expert_out = (float*)(base + 29360128);        //   reuse (21MB)
  ushort* qp  = pairs;
  ushort* kp  = pairs + 8388608;
  ushort* vtp = pairs + 2 * 8388608;
  float*  csum   = (float*)(base + 79691776);            // 128KB
  float*  vsufC  = (float*)(base + 79691776 + 131072);   // 139KB
  ushort* webf   = (ushort*)(base + 79691776 + 524288);  // 16.8MB (after attn)
  int*    routes = (int*)(base + 97255424);
  int*    slot   = routes + N;
  float*  rprob  = (float*)(slot + N);

  // 1. merged conversion: embed + Wq/Wk/Wv -> hi/lo pair arrays (1 launch)
  cvt_all<<<7168, 256, 0, stream>>>(embed, Wq, Wk, Wv, epair, wpair);
  // 2. merged QKV projection (split-bf16, N=3072) -> attention-layout pairs
  qkv_gemm<<<dim3(24, 32), 256, 0, stream>>>(epair, wpair, bq, bk, bv, pairs);
  // 3. chunk sums + chunk suffix of v (tail table for attention)
  vchunk_sum<<<dim3(32, 16), 64, 0, stream>>>(vtp, csum);
  vchunk_suffix<<<32, 64, 0, stream>>>(csum, vsufC);
  // 4. MFMA attention v3b -> hiddens (64KB LDS, 2 blocks/CU)
  attn_mfma<<<dim3(16, 32), 512, 0, stream>>>(qp, kp, vtp, vsufC, hid);
  // 5. router
  router_kernel<<<N / 4, 256, 0, stream>>>(hid, Wsw, bsw, routes, rprob);
  // 6. capacity scan
  scan_kernel<<<1, 256, 0, stream>>>(routes, slot);
  // 7. We -> bf16 (region free; runs after attn in stream order)
  cvt_plain<<<(int)((long long)E * D * D / 1024), 256, 0, stream>>>(We, webf);
  // 8. dispatch tokens -> expert_in (bf16)
  dispatch_kernel<<<N, 256, 0, stream>>>(hid, slot, expert_in);
  // 9. expert GEMMs: plain bf16 (K=1024), M padded to 640
  expert_gemm<<<dim3(8, ECAP / 128, E), 256, 0, stream>>>(
      expert_in, webf, be, expert_out);
  // 10. gather + combine + residual + LayerNorm
  finalize_kernel<<<N, 256, 0, stream>>>(hid, expert_out, slot, rprob,
                                         embed, gamma, beta, out);
}